// Round 13
// baseline (1934.668 us; speedup 1.0000x reference)
//
#include <hip/hip_runtime.h>
#include <math.h>

#define DI __device__ __forceinline__

constexpr int B = 16, H = 41, W = 40, C = 48, M1 = 12, M2 = 12, NL = 4;
constexpr int HW = H * W;                  // 1640
constexpr int NPART = 6;
constexpr float EPS = 1e-5f;
constexpr float PI_F = 3.14159265358979323846f;

// ---------------- static device scratch (compile-time shapes) ----------------
__device__ float  g_h[2][B * C * HW];      // ping-pong activations [b][c][hw]
__device__ float2 g_alpha[B * C * HW];     // fft2(inorm(h))
__device__ float2 g_inv1t[NL][C * C][H * 16];  // transposed inv1 [o*16+p] (pad 16)
__device__ float2 g_inv2a[NL][C * C][M2 * W];
__device__ float2 g_E1a[NL][C * C][M1 * H];    // [p][z]
__device__ float2 g_E2a[NL][C * C][M2 * W];    // [q][x]
__device__ float2 g_Sa[NL][C * C][HW];
__device__ float2 g_res1[B * C * HW];
__device__ float  g_x1[B * C * HW];        // pr2d output (real)
__device__ float2 g_r2[B * C * M1 * M2];
__device__ float2 g_Zr[C * C][B * M1 * M2]; // per-(i,k) res-scaled Z, reduced over i by k_r2b
__device__ float  g_xpart[NPART][B * C][HW];   // k_x2p partial sums over ci-sixths
__device__ float  g_mu[B * C];
__device__ float  g_rstd[B * C];
__device__ float2 g_wfh[H * H];            // e^{-2pi i o h / H}
__device__ float2 g_wfw[W * W];            // e^{-2pi i x w / W}

// ---------------- complex helpers ----------------
DI float2 cmadd(float2 a, float2 b, float2 acc) {
    acc.x = fmaf(a.x, b.x, fmaf(-a.y, b.y, acc.x));
    acc.y = fmaf(a.x, b.y, fmaf(a.y, b.x, acc.y));
    return acc;
}
DI float2 cmul(float2 a, float2 b) {
    return make_float2(a.x * b.x - a.y * b.y, a.x * b.y + a.y * b.x);
}

// ---------------- twiddle tables ----------------
__global__ void k_tw() {
    int tid = blockIdx.x * 256 + threadIdx.x;
    if (tid < H * H) {
        int o = tid / H, h = tid % H;
        float ph = -2.0f * PI_F * (float)((o * h) % H) / (float)H;
        float s, c; sincosf(ph, &s, &c);
        g_wfh[tid] = make_float2(c, s);
    }
    int t2 = tid - H * H;
    if (t2 >= 0 && t2 < W * W) {
        int o = t2 / W, w = t2 % W;
        float ph = -2.0f * PI_F * (float)((o * w) % W) / (float)W;
        float s, c; sincosf(ph, &s, &c);
        g_wfw[t2] = make_float2(c, s);
    }
}

// ---------------- fc0 + grid concat ----------------
__global__ void k_fc0(const float* __restrict__ x, const float* __restrict__ w,
                      const float* __restrict__ bias) {
    int idx = blockIdx.x * 256 + threadIdx.x;
    if (idx >= B * C * HW) return;
    int hw = idx % HW; int bc = idx / HW; int c = bc % C; int b = bc / C;
    int hh = hw / W, ww = hw % W;
    float xv = x[b * HW + hw];
    float gx = hh * (1.0f / (H - 1));
    float gy = ww * (1.0f / (W - 1));
    g_h[0][idx] = fmaf(w[c * 3 + 0], xv, fmaf(w[c * 3 + 1], gx, fmaf(w[c * 3 + 2], gy, bias[c])));
}

// ---------------- instance-norm + fft2, register-tiled DFTs ----------------
__global__ __launch_bounds__(256) void k_fft(int src) {
    int bid = blockIdx.x;                  // b*C + c
    const float* hp = &g_h[src][(size_t)bid * HW];
    __shared__ __align__(16) float sh[HW];
    __shared__ __align__(16) float2 st[HW];
    __shared__ __align__(16) float2 swf[H * H];   // wfh; later wfw stride-41
    __shared__ float red[8];
    int tid = threadIdx.x;
    float s = 0.f, ss = 0.f;
    for (int i = tid; i < HW; i += 256) { float v = hp[i]; sh[i] = v; s += v; ss += v * v; }
    for (int i = tid; i < H * H; i += 256) swf[i] = g_wfh[i];
    for (int off = 32; off; off >>= 1) { s += __shfl_down(s, off); ss += __shfl_down(ss, off); }
    if ((tid & 63) == 0) { red[tid >> 6] = s; red[4 + (tid >> 6)] = ss; }
    __syncthreads();
    if (tid == 0) {
        float S = red[0] + red[1] + red[2] + red[3];
        float SS = red[4] + red[5] + red[6] + red[7];
        float mean = S * (1.0f / HW);
        float var = SS * (1.0f / HW) - mean * mean;
        red[0] = mean; red[1] = rsqrtf(var + EPS);
    }
    __syncthreads();
    float mean = red[0], rstd = red[1];
    for (int i = tid; i < HW; i += 256) sh[i] = (sh[i] - mean) * rstd;
    __syncthreads();
    // row DFT: 2o x 4w tiles (210 threads): st[o,w] = sum_h wfh[o,h] * sh[h,w]
    if (tid < 210) {
        int op = tid / 10, wq = tid % 10;
        int o0 = op * 2, w0 = wq * 4;
        bool pair = (o0 + 1) < H;
        int o1 = pair ? o0 + 1 : o0;
        float2 a0[4], a1[4];
#pragma unroll
        for (int j = 0; j < 4; j++) { a0[j] = make_float2(0.f, 0.f); a1[j] = make_float2(0.f, 0.f); }
        for (int h = 0; h < H; h++) {
            float4 v = *(const float4*)&sh[h * W + w0];
            float2 t0 = swf[o0 * H + h];
            float2 t1 = swf[o1 * H + h];
            a0[0].x = fmaf(t0.x, v.x, a0[0].x); a0[0].y = fmaf(t0.y, v.x, a0[0].y);
            a0[1].x = fmaf(t0.x, v.y, a0[1].x); a0[1].y = fmaf(t0.y, v.y, a0[1].y);
            a0[2].x = fmaf(t0.x, v.z, a0[2].x); a0[2].y = fmaf(t0.y, v.z, a0[2].y);
            a0[3].x = fmaf(t0.x, v.w, a0[3].x); a0[3].y = fmaf(t0.y, v.w, a0[3].y);
            a1[0].x = fmaf(t1.x, v.x, a1[0].x); a1[0].y = fmaf(t1.y, v.x, a1[0].y);
            a1[1].x = fmaf(t1.x, v.y, a1[1].x); a1[1].y = fmaf(t1.y, v.y, a1[1].y);
            a1[2].x = fmaf(t1.x, v.z, a1[2].x); a1[2].y = fmaf(t1.y, v.z, a1[2].y);
            a1[3].x = fmaf(t1.x, v.w, a1[3].x); a1[3].y = fmaf(t1.y, v.w, a1[3].y);
        }
#pragma unroll
        for (int j = 0; j < 4; j++) st[o0 * W + w0 + j] = a0[j];
        if (pair) {
#pragma unroll
            for (int j = 0; j < 4; j++) st[o1 * W + w0 + j] = a1[j];
        }
    }
    __syncthreads();
    // stage wfw stride 41
    for (int t = tid; t < W * W; t += 256) {
        int x = t / W, w = t % W;
        swf[x * 41 + w] = g_wfw[t];
    }
    __syncthreads();
    // col DFT: 2o x 4x tiles (210 threads): alpha[o,x] = sum_w st[o,w] * wfw[x,w]
    float2* ap = &g_alpha[(size_t)bid * HW];
    if (tid < 210) {
        int op = tid / 10, xq = tid % 10;
        int o0 = op * 2, x0 = xq * 4;
        bool pair = (o0 + 1) < H;
        int o1 = pair ? o0 + 1 : o0;
        float2 c0[4], c1[4];
#pragma unroll
        for (int j = 0; j < 4; j++) { c0[j] = make_float2(0.f, 0.f); c1[j] = make_float2(0.f, 0.f); }
        for (int w = 0; w < W; w++) {
            float2 s0v = st[o0 * W + w];
            float2 s1v = st[o1 * W + w];
#pragma unroll
            for (int j = 0; j < 4; j++) {
                float2 e = swf[(x0 + j) * 41 + w];
                c0[j] = cmadd(s0v, e, c0[j]);
                c1[j] = cmadd(s1v, e, c1[j]);
            }
        }
#pragma unroll
        for (int j = 0; j < 4; j++) ap[o0 * W + x0 + j] = c0[j];
        if (pair) {
#pragma unroll
            for (int j = 0; j < 4; j++) ap[o1 * W + x0 + j] = c1[j];
        }
    }
}

// ---------------- k_tbS: ALL layers' pole tables + S, one dispatch ----------------
__global__ __launch_bounds__(256) void k_tbS(const float* __restrict__ p1, const float* __restrict__ p2,
                                             const float* __restrict__ res_in) {
    int gb = blockIdx.x;                   // l*C*C + pk
    int l = gb / (C * C), pk = gb % (C * C);
    int tid = threadIdx.x;
    __shared__ float2 sinv1[M1 * H];       // [p*H+o]
    __shared__ float2 sinv2[M2 * W];       // [q*W+x]
    __shared__ float2 sT[M1 * W];
    __shared__ float2 sres[M1 * M2];
    const float* pp1 = p1 + (size_t)gb * M1 * 2;
    const float* pp2 = p2 + (size_t)gb * M2 * 2;
    for (int t = tid; t < M1 * H; t += 256) {
        int p = t / H, o = t % H;
        float pr = pp1[p * 2], pi = pp1[p * 2 + 1];
        int ko = (o <= H / 2) ? o : o - H;           // fftfreq, H=41 odd
        float lam = (40.0f / 41.0f) * (float)ko;     // Im(LAM1)
        float a = -pr, b = lam - pi;
        float d = 1.0f / (a * a + b * b);
        float2 inv = make_float2(a * d, -b * d);
        sinv1[t] = inv;
        float tt = o * (2.0f * PI_F / (H - 1));      // TX[z]
        float er = expf(pr * tt);
        float sn, cs; sincosf(pi * tt, &sn, &cs);
        g_E1a[l][pk][t] = make_float2(er * cs, er * sn);
    }
    for (int t = tid; t < M2 * W; t += 256) {
        int q = t / W, x = t % W;
        float pr = pp2[q * 2], pi = pp2[q * 2 + 1];
        int kx = (x < W / 2) ? x : x - W;            // fftfreq, W=40 even
        float lam = (2.0f * PI_F * 39.0f / 600.0f) * (float)kx;  // Im(LAM2)
        float a = -pr, b = lam - pi;
        float d = 1.0f / (a * a + b * b);
        float2 inv = make_float2(a * d, -b * d);
        sinv2[t] = inv;
        g_inv2a[l][pk][t] = inv;
        float tt = x * (15.0f / (W - 1));            // TY[x]
        float er = expf(pr * tt);
        float sn, cs; sincosf(pi * tt, &sn, &cs);
        g_E2a[l][pk][t] = make_float2(er * cs, er * sn);
    }
    const float2* rp = (const float2*)res_in + (size_t)gb * M1 * M2;
    for (int t = tid; t < M1 * M2; t += 256) sres[t] = rp[t];
    __syncthreads();
    // coalesced transposed inv1 write
    for (int t = tid; t < H * 16; t += 256) {
        int o = t >> 4, p = t & 15;
        g_inv1t[l][pk][t] = (p < M1) ? sinv1[p * H + o] : make_float2(0.f, 0.f);
    }
    // T[p,x] = sum_q res[p,q] inv2[q,x]
    for (int t = tid; t < M1 * W; t += 256) {
        int p = t / W, x = t % W;
        float2 acc = make_float2(0.f, 0.f);
        for (int q = 0; q < M2; q++) acc = cmadd(sres[p * M2 + q], sinv2[q * W + x], acc);
        sT[t] = acc;
    }
    __syncthreads();
    // S[o,x] = sum_p inv1[p,o] * T[p,x]
    float2* sp = g_Sa[l][pk];
    for (int t = tid; t < HW; t += 256) {
        int o = t / W, x = t % W;
        float2 acc = make_float2(0.f, 0.f);
        for (int p = 0; p < M1; p++) acc = cmadd(sinv1[p * H + o], sT[p * W + x], acc);
        sp[t] = acc;
    }
}

// ---------------- k_res1 v3: 2b x 4k register tile ----------------
__global__ __launch_bounds__(256) void k_res1(int l) {
    int bid = blockIdx.x;
    int ch = bid % 7;
    int rest = bid / 7;                            // 0..95
    int kq = rest % 12, bp = rest / 12;            // bp 0..7
    int hw = ch * 256 + threadIdx.x;
    if (hw >= HW) return;
    int b0 = bp * 2, k0 = kq * 4;
    float2 acc[2][4];
#pragma unroll
    for (int u = 0; u < 2; u++)
#pragma unroll
        for (int v = 0; v < 4; v++) acc[u][v] = make_float2(0.f, 0.f);
    for (int i = 0; i < C; i++) {
        float2 a0 = g_alpha[(size_t)((b0    ) * C + i) * HW + hw];
        float2 a1 = g_alpha[(size_t)((b0 + 1) * C + i) * HW + hw];
        float2 s0 = g_Sa[l][i * C + k0][hw];
        float2 s1 = g_Sa[l][i * C + k0 + 1][hw];
        float2 s2 = g_Sa[l][i * C + k0 + 2][hw];
        float2 s3 = g_Sa[l][i * C + k0 + 3][hw];
        acc[0][0] = cmadd(a0, s0, acc[0][0]);
        acc[0][1] = cmadd(a0, s1, acc[0][1]);
        acc[0][2] = cmadd(a0, s2, acc[0][2]);
        acc[0][3] = cmadd(a0, s3, acc[0][3]);
        acc[1][0] = cmadd(a1, s0, acc[1][0]);
        acc[1][1] = cmadd(a1, s1, acc[1][1]);
        acc[1][2] = cmadd(a1, s2, acc[1][2]);
        acc[1][3] = cmadd(a1, s3, acc[1][3]);
    }
#pragma unroll
    for (int u = 0; u < 2; u++)
#pragma unroll
        for (int v = 0; v < 4; v++)
            g_res1[(size_t)((b0 + u) * C + k0 + v) * HW + hw] = acc[u][v];
}

// ---------------- k_ifftfin: x1 = ifft2(res1).real + xparts; stats (fused, tiled) --------
__global__ __launch_bounds__(256) void k_ifftfin() {
    int bid = blockIdx.x; int tid = threadIdx.x;
    __shared__ __align__(16) float2 s0[HW], s1[HW];
    __shared__ __align__(16) float2 swf[H * H];   // wfh; later wfw stride-42
    __shared__ float red[8];
    const float2* rp = &g_res1[(size_t)bid * HW];
    for (int i = tid; i < HW; i += 256) s0[i] = rp[i];
    for (int i = tid; i < H * H; i += 256) swf[i] = g_wfh[i];
    __syncthreads();
    // inverse over o: 2h x 4x tiles (210 threads)
    if (tid < 210) {
        int hp = tid / 10, xq = tid % 10;
        int h0 = hp * 2, x0 = xq * 4;
        bool pair = (h0 + 1) < H;
        int h1 = pair ? h0 + 1 : h0;
        float2 a0[4], a1[4];
#pragma unroll
        for (int j = 0; j < 4; j++) { a0[j] = make_float2(0.f, 0.f); a1[j] = make_float2(0.f, 0.f); }
        for (int o = 0; o < H; o++) {
            float4 v01 = *(const float4*)&s0[o * W + x0];
            float4 v23 = *(const float4*)&s0[o * W + x0 + 2];
            float2 t0 = swf[o * H + h0];
            float2 t1 = swf[o * H + h1];
            a0[0].x = fmaf(v01.x, t0.x, fmaf(v01.y, t0.y, a0[0].x));
            a0[0].y = fmaf(v01.y, t0.x, fmaf(-v01.x, t0.y, a0[0].y));
            a0[1].x = fmaf(v01.z, t0.x, fmaf(v01.w, t0.y, a0[1].x));
            a0[1].y = fmaf(v01.w, t0.x, fmaf(-v01.z, t0.y, a0[1].y));
            a0[2].x = fmaf(v23.x, t0.x, fmaf(v23.y, t0.y, a0[2].x));
            a0[2].y = fmaf(v23.y, t0.x, fmaf(-v23.x, t0.y, a0[2].y));
            a0[3].x = fmaf(v23.z, t0.x, fmaf(v23.w, t0.y, a0[3].x));
            a0[3].y = fmaf(v23.w, t0.x, fmaf(-v23.z, t0.y, a0[3].y));
            a1[0].x = fmaf(v01.x, t1.x, fmaf(v01.y, t1.y, a1[0].x));
            a1[0].y = fmaf(v01.y, t1.x, fmaf(-v01.x, t1.y, a1[0].y));
            a1[1].x = fmaf(v01.z, t1.x, fmaf(v01.w, t1.y, a1[1].x));
            a1[1].y = fmaf(v01.w, t1.x, fmaf(-v01.z, t1.y, a1[1].y));
            a1[2].x = fmaf(v23.x, t1.x, fmaf(v23.y, t1.y, a1[2].x));
            a1[2].y = fmaf(v23.y, t1.x, fmaf(-v23.x, t1.y, a1[2].y));
            a1[3].x = fmaf(v23.z, t1.x, fmaf(v23.w, t1.y, a1[3].x));
            a1[3].y = fmaf(v23.w, t1.x, fmaf(-v23.z, t1.y, a1[3].y));
        }
#pragma unroll
        for (int j = 0; j < 4; j++) s1[h0 * W + x0 + j] = a0[j];
        if (pair) {
#pragma unroll
            for (int j = 0; j < 4; j++) s1[h1 * W + x0 + j] = a1[j];
        }
    }
    __syncthreads();
    // stage wfw stride 42 (16B-aligned rows)
    for (int t = tid; t < W * W; t += 256) {
        int x = t / W, w = t % W;
        swf[x * 42 + w] = g_wfw[t];
    }
    __syncthreads();
    // inverse over x: 2h x 4w tiles + xpart combine + stats
    float* xp = &g_x1[(size_t)bid * HW];
    float s = 0.f, ss = 0.f;
    if (tid < 210) {
        int hp = tid / 10, wq = tid % 10;
        int h0 = hp * 2, w0 = wq * 4;
        bool pair = (h0 + 1) < H;
        int h1 = pair ? h0 + 1 : h0;
        float acc0[4] = {0.f, 0.f, 0.f, 0.f}, acc1[4] = {0.f, 0.f, 0.f, 0.f};
        for (int x = 0; x < W; x++) {
            float2 u0 = s1[h0 * W + x];
            float2 u1 = s1[h1 * W + x];
            float4 e01 = *(const float4*)&swf[x * 42 + w0];
            float4 e23 = *(const float4*)&swf[x * 42 + w0 + 2];
            acc0[0] = fmaf(u0.x, e01.x, fmaf(u0.y, e01.y, acc0[0]));
            acc0[1] = fmaf(u0.x, e01.z, fmaf(u0.y, e01.w, acc0[1]));
            acc0[2] = fmaf(u0.x, e23.x, fmaf(u0.y, e23.y, acc0[2]));
            acc0[3] = fmaf(u0.x, e23.z, fmaf(u0.y, e23.w, acc0[3]));
            acc1[0] = fmaf(u1.x, e01.x, fmaf(u1.y, e01.y, acc1[0]));
            acc1[1] = fmaf(u1.x, e01.z, fmaf(u1.y, e01.w, acc1[1]));
            acc1[2] = fmaf(u1.x, e23.x, fmaf(u1.y, e23.y, acc1[2]));
            acc1[3] = fmaf(u1.x, e23.z, fmaf(u1.y, e23.w, acc1[3]));
        }
        {
            int base = h0 * W + w0;
            float4 q0 = *(const float4*)&g_xpart[0][bid][base];
            float4 q1 = *(const float4*)&g_xpart[1][bid][base];
            float4 q2 = *(const float4*)&g_xpart[2][bid][base];
            float4 q3 = *(const float4*)&g_xpart[3][bid][base];
            float4 q4 = *(const float4*)&g_xpart[4][bid][base];
            float4 q5 = *(const float4*)&g_xpart[5][bid][base];
            float vv[4];
            vv[0] = (acc0[0] + q0.x + q1.x + q2.x + q3.x + q4.x + q5.x) * (1.0f / (H * W));
            vv[1] = (acc0[1] + q0.y + q1.y + q2.y + q3.y + q4.y + q5.y) * (1.0f / (H * W));
            vv[2] = (acc0[2] + q0.z + q1.z + q2.z + q3.z + q4.z + q5.z) * (1.0f / (H * W));
            vv[3] = (acc0[3] + q0.w + q1.w + q2.w + q3.w + q4.w + q5.w) * (1.0f / (H * W));
#pragma unroll
            for (int j = 0; j < 4; j++) { xp[base + j] = vv[j]; s += vv[j]; ss += vv[j] * vv[j]; }
        }
        if (pair) {
            int base = h1 * W + w0;
            float4 q0 = *(const float4*)&g_xpart[0][bid][base];
            float4 q1 = *(const float4*)&g_xpart[1][bid][base];
            float4 q2 = *(const float4*)&g_xpart[2][bid][base];
            float4 q3 = *(const float4*)&g_xpart[3][bid][base];
            float4 q4 = *(const float4*)&g_xpart[4][bid][base];
            float4 q5 = *(const float4*)&g_xpart[5][bid][base];
            float vv[4];
            vv[0] = (acc1[0] + q0.x + q1.x + q2.x + q3.x + q4.x + q5.x) * (1.0f / (H * W));
            vv[1] = (acc1[1] + q0.y + q1.y + q2.y + q3.y + q4.y + q5.y) * (1.0f / (H * W));
            vv[2] = (acc1[2] + q0.z + q1.z + q2.z + q3.z + q4.z + q5.z) * (1.0f / (H * W));
            vv[3] = (acc1[3] + q0.w + q1.w + q2.w + q3.w + q4.w + q5.w) * (1.0f / (H * W));
#pragma unroll
            for (int j = 0; j < 4; j++) { xp[base + j] = vv[j]; s += vv[j]; ss += vv[j] * vv[j]; }
        }
    }
    for (int off = 32; off; off >>= 1) { s += __shfl_down(s, off); ss += __shfl_down(ss, off); }
    if ((tid & 63) == 0) { red[tid >> 6] = s; red[4 + (tid >> 6)] = ss; }
    __syncthreads();
    if (tid == 0) {
        float S = red[0] + red[1] + red[2] + red[3];
        float SS = red[4] + red[5] + red[6] + red[7];
        float mean = S * (1.0f / HW);
        float var = SS * (1.0f / HW) - mean * mean;
        g_mu[bid] = mean; g_rstd[bid] = rsqrtf(var + EPS);
    }
}

// ---------------- k_r2a v7: alpha preloaded to registers before barrier ----------
// grid C*C*4, 320 threads. Y: all lanes, alpha[41] in regs (loads hide under staging+barrier).
__global__ __launch_bounds__(320) void k_r2a(const float* __restrict__ res_in, int l) {
    // XCD-aware remap: same-i blocks on one XCD (alpha[:,i] slices L2-resident)
    int bid = blockIdx.x;
    int xcd = bid & 7, idx = bid >> 3;             // idx 0..1151
    int i = (idx / (C * 4)) * 8 + xcd;             // 6 i's per XCD
    int rem = idx % (C * 4);
    int k = rem >> 2;
    int bc = rem & 3;                              // b-chunk: b = bc*4 .. bc*4+3
    int pk = i * C + k;
    int tid = threadIdx.x;
    __shared__ float2 sY[4 * M1 * 41];             // 15.7 KB
    __shared__ float2 si1t[H * 16];                // transposed inv1 [o][p], 16-padded
    __shared__ float2 si2[M2 * 41];                // [q*41 + x]
    __shared__ float2 sres[M1 * M2];
    // ---- issue alpha register loads FIRST (latency hides under staging + barrier) ----
    int ph = tid / 160;                            // p-half: p0 = ph*6
    int r2t = tid % 160;
    int bloc = r2t / 40, x = r2t % 40;
    int b = bc * 4 + bloc;
    int p0 = ph * 6;
    const float2* ap = &g_alpha[(size_t)(b * C + i) * HW + x];
    float2 av[H];
#pragma unroll
    for (int o = 0; o < H; o++) av[o] = ap[o * W];
    // ---- LDS staging ----
    for (int t = tid; t < H * 16; t += 320) si1t[t] = g_inv1t[l][pk][t];
    for (int t = tid; t < M2 * W; t += 320) {
        int q = t / W, xx = t % W;
        si2[q * 41 + xx] = g_inv2a[l][pk][t];
    }
    const float2* rp = (const float2*)res_in + (size_t)(l * C * C + pk) * M1 * M2;
    for (int t = tid; t < M1 * M2; t += 320) sres[t] = rp[t];
    __syncthreads();
    // ---- Y phase: pure LDS + FMA ----
    {
        float2 yacc[6];
#pragma unroll
        for (int p = 0; p < 6; p++) yacc[p] = make_float2(0.f, 0.f);
#pragma unroll
        for (int o = 0; o < H; o++) {
            float2 a = av[o];
            const float4* e4 = (const float4*)&si1t[o * 16 + p0];
            float4 e0 = e4[0], e1 = e4[1], e2 = e4[2];
            yacc[0] = cmadd(make_float2(e0.x, e0.y), a, yacc[0]);
            yacc[1] = cmadd(make_float2(e0.z, e0.w), a, yacc[1]);
            yacc[2] = cmadd(make_float2(e1.x, e1.y), a, yacc[2]);
            yacc[3] = cmadd(make_float2(e1.z, e1.w), a, yacc[3]);
            yacc[4] = cmadd(make_float2(e2.x, e2.y), a, yacc[4]);
            yacc[5] = cmadd(make_float2(e2.z, e2.w), a, yacc[5]);
        }
#pragma unroll
        for (int p = 0; p < 6; p++) sY[(bloc * M1 + p0 + p) * 41 + x] = yacc[p];
    }
    __syncthreads();
    // ---- Z phase: 288 threads = (bloc4 x p12 x qh6), 2 q-accs ----
    if (tid < 288) {
        int zbloc = tid / 72, rem2 = tid % 72;
        int p = rem2 / 6, qh = rem2 % 6;
        int q0 = qh * 2;
        float2 zacc0 = make_float2(0.f, 0.f), zacc1 = make_float2(0.f, 0.f);
        const float2* yrow = &sY[(zbloc * M1 + p) * 41];
        const float2* s2a = &si2[q0 * 41];
        const float2* s2b = &si2[(q0 + 1) * 41];
        for (int xx = 0; xx < W; xx++) {
            float2 y = yrow[xx];
            zacc0 = cmadd(y, s2a[xx], zacc0);
            zacc1 = cmadd(y, s2b[xx], zacc1);
        }
        int zb = bc * 4 + zbloc;
        float2* out = &g_Zr[pk][zb * (M1 * M2) + p * M2 + q0];
        out[0] = cmul(sres[p * M2 + q0], zacc0);
        out[1] = cmul(sres[p * M2 + q0 + 1], zacc1);
    }
}

// ---------------- k_r2b: r2[b,k,p,q] = sum_i Zr[i*C+k][b,p,q] ----------------
__global__ __launch_bounds__(256) void k_r2b() {
    int t = blockIdx.x * 256 + threadIdx.x;        // < B*C*144
    if (t >= B * C * M1 * M2) return;
    int pq = t % (M1 * M2);
    int k = (t / (M1 * M2)) % C;
    int b = t / (M1 * M2 * C);
    float2 acc = make_float2(0.f, 0.f);
    for (int i = 0; i < C; i++) {
        float2 v = g_Zr[i * C + k][b * (M1 * M2) + pq];
        acc.x += v.x; acc.y += v.y;
    }
    g_r2[(size_t)(b * C + k) * (M1 * M2) + pq] = acc;
}

// ---------------- k_x2p: 6 parts (grid 4608) ----------
constexpr int XNCI = 2;
__global__ __launch_bounds__(256) void k_x2p(int l) {
    int bid = blockIdx.x;
    int xcd = bid & 7, rest = bid >> 3;            // 0..575
    int part = rest % NPART;
    int idx = rest / NPART;                        // 0..95
    int k = (idx / B) * 8 + xcd;
    int b = idx % B;
    int tid = threadIdx.x;
    __shared__ float2 sE1[XNCI * M1 * 44];         // [jp][z], z-padded to 44 (zeros)
    __shared__ float2 sV [XNCI * M1 * 40];         // [jp][x]
    __shared__ float2 sE2[XNCI * M2 * 41];         // [jq][x]
    __shared__ float2 sr2[XNCI * M1 * M2];
    int xh = tid % 20, zq = tid / 20;              // active: tid<240
    int x0 = xh * 2, z0 = zq * 4;
    float accr[4][2];
#pragma unroll
    for (int zi = 0; zi < 4; zi++) { accr[zi][0] = 0.f; accr[zi][1] = 0.f; }

    int cg0 = part * (C / XNCI / NPART);           // 4 cg groups per part
    for (int cg = cg0; cg < cg0 + C / XNCI / NPART; cg++) {
        for (int t = tid; t < XNCI * M1 * 44; t += 256) {
            int j = t / (M1 * 44), rem = t % (M1 * 44);
            int p = rem / 44, z = rem % 44;
            sE1[t] = (z < H) ? g_E1a[l][(cg * XNCI + j) * C + k][p * H + z]
                             : make_float2(0.f, 0.f);
        }
        for (int t = tid; t < XNCI * M2 * W; t += 256) {
            int j = t / (M2 * W), rem = t % (M2 * W);
            sE2[(t / W) * 41 + (t % W)] = g_E2a[l][(cg * XNCI + j) * C + k][rem];
        }
        for (int t = tid; t < XNCI * M1 * M2; t += 256) {
            int j = t / (M1 * M2);
            sr2[t] = g_r2[(size_t)(b * C + cg * XNCI + j) * (M1 * M2) + (t % (M1 * M2))];
        }
        __syncthreads();
        // V[j,p,x] for p-pairs: one sE2 read feeds 2 outputs
        for (int r = 0; r < 2; r++) {
            int id = tid + r * 256;
            if (id < XNCI * 6 * W) {
                int j = id / (6 * W), rem = id % (6 * W);
                int pp = rem / W, x = rem % W;
                int p0 = pp * 2;
                float2 a0 = make_float2(0.f, 0.f), a1 = make_float2(0.f, 0.f);
#pragma unroll
                for (int q = 0; q < M2; q++) {
                    float2 e = sE2[(j * M2 + q) * 41 + x];
                    a0 = cmadd(sr2[j * (M1 * M2) + p0 * M2 + q], e, a0);
                    a1 = cmadd(sr2[j * (M1 * M2) + (p0 + 1) * M2 + q], e, a1);
                }
                sV[(j * M1 + p0) * 40 + x] = a0;
                sV[(j * M1 + p0 + 1) * 40 + x] = a1;
            }
        }
        __syncthreads();
        // accr[z,x] += Re( E1[jp][z] * V[jp][x] )
        if (tid < 240 && z0 < H) {
            for (int jp = 0; jp < XNCI * M1; jp++) {
                float4 v  = *(const float4*)&sV[jp * 40 + x0];
                float4 eA = *(const float4*)&sE1[jp * 44 + z0];
                float4 eB = *(const float4*)&sE1[jp * 44 + z0 + 2];
                accr[0][0] = fmaf(eA.x, v.x, fmaf(-eA.y, v.y, accr[0][0]));
                accr[0][1] = fmaf(eA.x, v.z, fmaf(-eA.y, v.w, accr[0][1]));
                accr[1][0] = fmaf(eA.z, v.x, fmaf(-eA.w, v.y, accr[1][0]));
                accr[1][1] = fmaf(eA.z, v.z, fmaf(-eA.w, v.w, accr[1][1]));
                accr[2][0] = fmaf(eB.x, v.x, fmaf(-eB.y, v.y, accr[2][0]));
                accr[2][1] = fmaf(eB.x, v.z, fmaf(-eB.y, v.w, accr[2][1]));
                accr[3][0] = fmaf(eB.z, v.x, fmaf(-eB.w, v.y, accr[3][0]));
                accr[3][1] = fmaf(eB.z, v.z, fmaf(-eB.w, v.w, accr[3][1]));
            }
        }
        __syncthreads();
    }
    float* op = &g_xpart[part][b * C + k][0];
    if (tid < 240 && z0 < H) {
#pragma unroll
        for (int zi = 0; zi < 4; zi++) {
            int z = z0 + zi;
            if (z < H) { op[z * W + x0] = accr[zi][0]; op[z * W + x0 + 1] = accr[zi][1]; }
        }
    }
}

// ---------------- h_next = sin( inorm(pr) + conv(h) + conv_b ) ----------------
constexpr int TILE = 128;
constexpr int NTILE = (HW + TILE - 1) / TILE;   // 13
__global__ __launch_bounds__(256) void k_comb(const float* __restrict__ cw,
                                              const float* __restrict__ cb, int l, int src) {
    int b = blockIdx.x / NTILE;
    int t0 = (blockIdx.x % NTILE) * TILE;
    int tid = threadIdx.x;
    __shared__ float shh[C * TILE];
    __shared__ float scw[C * C];
    __shared__ float smu[C], srs[C], scb[C];
    for (int i = tid; i < C * C; i += 256) scw[i] = cw[l * C * C + i];
    for (int i = tid; i < C; i += 256) {
        smu[i] = g_mu[b * C + i]; srs[i] = g_rstd[b * C + i]; scb[i] = cb[l * C + i];
    }
    for (int i = tid; i < C * TILE; i += 256) {
        int c = i / TILE, t = i % TILE; int hw = t0 + t;
        shh[i] = (hw < HW) ? g_h[src][(size_t)(b * C + c) * HW + hw] : 0.f;
    }
    __syncthreads();
    for (int i = tid; i < C * TILE; i += 256) {
        int o = i / TILE, t = i % TILE; int hw = t0 + t;
        if (hw >= HW) continue;
        float acc = scb[o];
        for (int ci = 0; ci < C; ci++) acc = fmaf(scw[o * C + ci], shh[ci * TILE + t], acc);
        float prn = (g_x1[(size_t)(b * C + o) * HW + hw] - smu[o]) * srs[o];
        g_h[src ^ 1][(size_t)(b * C + o) * HW + hw] = sinf(prn + acc);
    }
}

// ---------------- head: out = fc2( sin(fc1(h)) ) ----------------
__global__ __launch_bounds__(256) void k_head(const float* __restrict__ w1, const float* __restrict__ b1,
                                              const float* __restrict__ w2, const float* __restrict__ b2,
                                              float* __restrict__ out, int src) {
    __shared__ float sw1[128 * C];
    __shared__ float sb1[128], sw2[2 * 128];
    int tid = threadIdx.x;
    for (int i = tid; i < 128 * C; i += 256) sw1[i] = w1[i];
    for (int i = tid; i < 128; i += 256) sb1[i] = b1[i];
    for (int i = tid; i < 256; i += 256) sw2[i] = w2[i];
    __syncthreads();
    int pt = blockIdx.x * 256 + tid;               // b*HW + hw
    if (pt >= B * HW) return;
    int b = pt / HW, hw = pt % HW;
    float hv[C];
#pragma unroll
    for (int c = 0; c < C; c++) hv[c] = g_h[src][(size_t)(b * C + c) * HW + hw];
    float o0 = b2[0], o1 = b2[1];
    for (int j = 0; j < 128; j++) {
        float a = sb1[j];
#pragma unroll
        for (int c = 0; c < C; c++) a = fmaf(sw1[j * C + c], hv[c], a);
        float sv = sinf(a);
        o0 = fmaf(sw2[j], sv, o0);
        o1 = fmaf(sw2[128 + j], sv, o1);
    }
    out[pt * 2 + 0] = o0; out[pt * 2 + 1] = o1;
}

// ---------------- launcher ----------------
extern "C" void kernel_launch(void* const* d_in, const int* in_sizes, int n_in,
                              void* d_out, int out_size, void* d_ws, size_t ws_size,
                              hipStream_t stream) {
    const float* x    = (const float*)d_in[0];
    const float* fc0w = (const float*)d_in[1];
    const float* fc0b = (const float*)d_in[2];
    const float* p1   = (const float*)d_in[3];
    const float* p2   = (const float*)d_in[4];
    const float* res  = (const float*)d_in[5];
    const float* cw   = (const float*)d_in[6];
    const float* cb   = (const float*)d_in[7];
    const float* w1   = (const float*)d_in[8];
    const float* b1   = (const float*)d_in[9];
    const float* w2   = (const float*)d_in[10];
    const float* b2   = (const float*)d_in[11];
    float* out = (float*)d_out;

    k_tw<<<(H * H + W * W + 255) / 256, 256, 0, stream>>>();
    k_fc0<<<(B * C * HW + 255) / 256, 256, 0, stream>>>(x, fc0w, fc0b);
    k_tbS<<<NL * C * C, 256, 0, stream>>>(p1, p2, res);   // all layers' tables, once
    int src = 0;
    for (int l = 0; l < NL; l++) {
        k_fft<<<B * C, 256, 0, stream>>>(src);
        k_res1<<<672, 256, 0, stream>>>(l);
        k_r2a<<<C * C * 4, 320, 0, stream>>>(res, l);
        k_r2b<<<(B * C * M1 * M2 + 255) / 256, 256, 0, stream>>>();
        k_x2p<<<NPART * B * C, 256, 0, stream>>>(l);
        k_ifftfin<<<B * C, 256, 0, stream>>>();
        k_comb<<<B * NTILE, 256, 0, stream>>>(cw, cb, l, src);
        src ^= 1;
    }
    k_head<<<(B * HW + 255) / 256, 256, 0, stream>>>(w1, b1, w2, b2, out, src);
}

// Round 14
// 1692.503 us; speedup vs baseline: 1.1431x; 1.1431x over previous
//
#include <hip/hip_runtime.h>
#include <math.h>

#define DI __device__ __forceinline__

constexpr int B = 16, H = 41, W = 40, C = 48, M1 = 12, M2 = 12, NL = 4;
constexpr int HW = H * W;                  // 1640
constexpr int NPART = 6;
constexpr float EPS = 1e-5f;
constexpr float PI_F = 3.14159265358979323846f;

// ---------------- static device scratch (compile-time shapes) ----------------
__device__ float  g_h[2][B * C * HW];      // ping-pong activations [b][c][hw]
__device__ float2 g_alpha[B * C * HW];     // fft2(inorm(h))
__device__ float2 g_inv1t[NL][C * C][H * 16];  // transposed inv1 [o*16+p] (pad 16)
__device__ float2 g_inv2a[NL][C * C][M2 * W];
__device__ float2 g_E1a[NL][C * C][M1 * H];    // [p][z]
__device__ float2 g_E2a[NL][C * C][M2 * W];    // [q][x]
__device__ float2 g_Sa[NL][C * C][HW];
__device__ float2 g_res1[B * C * HW];
__device__ float  g_x1[B * C * HW];        // pr2d output (real)
__device__ float2 g_r2[B * C * M1 * M2];
__device__ float2 g_Zr[C * C][B * M1 * M2]; // per-(i,k) res-scaled Z, reduced over i by k_r2b
__device__ float  g_xpart[NPART][B * C][HW];   // k_x2p partial sums over ci-sixths
__device__ float  g_mu[B * C];
__device__ float  g_rstd[B * C];
__device__ float2 g_wfh[H * H];            // e^{-2pi i o h / H}
__device__ float2 g_wfw[W * W];            // e^{-2pi i x w / W}

// ---------------- complex helpers ----------------
DI float2 cmadd(float2 a, float2 b, float2 acc) {
    acc.x = fmaf(a.x, b.x, fmaf(-a.y, b.y, acc.x));
    acc.y = fmaf(a.x, b.y, fmaf(a.y, b.x, acc.y));
    return acc;
}
DI float2 cmul(float2 a, float2 b) {
    return make_float2(a.x * b.x - a.y * b.y, a.x * b.y + a.y * b.x);
}

// ---------------- twiddle tables ----------------
__global__ void k_tw() {
    int tid = blockIdx.x * 256 + threadIdx.x;
    if (tid < H * H) {
        int o = tid / H, h = tid % H;
        float ph = -2.0f * PI_F * (float)((o * h) % H) / (float)H;
        float s, c; sincosf(ph, &s, &c);
        g_wfh[tid] = make_float2(c, s);
    }
    int t2 = tid - H * H;
    if (t2 >= 0 && t2 < W * W) {
        int o = t2 / W, w = t2 % W;
        float ph = -2.0f * PI_F * (float)((o * w) % W) / (float)W;
        float s, c; sincosf(ph, &s, &c);
        g_wfw[t2] = make_float2(c, s);
    }
}

// ---------------- fc0 + grid concat ----------------
__global__ void k_fc0(const float* __restrict__ x, const float* __restrict__ w,
                      const float* __restrict__ bias) {
    int idx = blockIdx.x * 256 + threadIdx.x;
    if (idx >= B * C * HW) return;
    int hw = idx % HW; int bc = idx / HW; int c = bc % C; int b = bc / C;
    int hh = hw / W, ww = hw % W;
    float xv = x[b * HW + hw];
    float gx = hh * (1.0f / (H - 1));
    float gy = ww * (1.0f / (W - 1));
    g_h[0][idx] = fmaf(w[c * 3 + 0], xv, fmaf(w[c * 3 + 1], gx, fmaf(w[c * 3 + 2], gy, bias[c])));
}

// ---------------- instance-norm + fft2, register-tiled DFTs ----------------
__global__ __launch_bounds__(256) void k_fft(int src) {
    int bid = blockIdx.x;                  // b*C + c
    const float* hp = &g_h[src][(size_t)bid * HW];
    __shared__ __align__(16) float sh[HW];
    __shared__ __align__(16) float2 st[HW];
    __shared__ __align__(16) float2 swf[H * H];   // wfh; later wfw stride-41
    __shared__ float red[8];
    int tid = threadIdx.x;
    float s = 0.f, ss = 0.f;
    for (int i = tid; i < HW; i += 256) { float v = hp[i]; sh[i] = v; s += v; ss += v * v; }
    for (int i = tid; i < H * H; i += 256) swf[i] = g_wfh[i];
    for (int off = 32; off; off >>= 1) { s += __shfl_down(s, off); ss += __shfl_down(ss, off); }
    if ((tid & 63) == 0) { red[tid >> 6] = s; red[4 + (tid >> 6)] = ss; }
    __syncthreads();
    if (tid == 0) {
        float S = red[0] + red[1] + red[2] + red[3];
        float SS = red[4] + red[5] + red[6] + red[7];
        float mean = S * (1.0f / HW);
        float var = SS * (1.0f / HW) - mean * mean;
        red[0] = mean; red[1] = rsqrtf(var + EPS);
    }
    __syncthreads();
    float mean = red[0], rstd = red[1];
    for (int i = tid; i < HW; i += 256) sh[i] = (sh[i] - mean) * rstd;
    __syncthreads();
    // row DFT: 2o x 4w tiles (210 threads): st[o,w] = sum_h wfh[o,h] * sh[h,w]
    if (tid < 210) {
        int op = tid / 10, wq = tid % 10;
        int o0 = op * 2, w0 = wq * 4;
        bool pair = (o0 + 1) < H;
        int o1 = pair ? o0 + 1 : o0;
        float2 a0[4], a1[4];
#pragma unroll
        for (int j = 0; j < 4; j++) { a0[j] = make_float2(0.f, 0.f); a1[j] = make_float2(0.f, 0.f); }
        for (int h = 0; h < H; h++) {
            float4 v = *(const float4*)&sh[h * W + w0];
            float2 t0 = swf[o0 * H + h];
            float2 t1 = swf[o1 * H + h];
            a0[0].x = fmaf(t0.x, v.x, a0[0].x); a0[0].y = fmaf(t0.y, v.x, a0[0].y);
            a0[1].x = fmaf(t0.x, v.y, a0[1].x); a0[1].y = fmaf(t0.y, v.y, a0[1].y);
            a0[2].x = fmaf(t0.x, v.z, a0[2].x); a0[2].y = fmaf(t0.y, v.z, a0[2].y);
            a0[3].x = fmaf(t0.x, v.w, a0[3].x); a0[3].y = fmaf(t0.y, v.w, a0[3].y);
            a1[0].x = fmaf(t1.x, v.x, a1[0].x); a1[0].y = fmaf(t1.y, v.x, a1[0].y);
            a1[1].x = fmaf(t1.x, v.y, a1[1].x); a1[1].y = fmaf(t1.y, v.y, a1[1].y);
            a1[2].x = fmaf(t1.x, v.z, a1[2].x); a1[2].y = fmaf(t1.y, v.z, a1[2].y);
            a1[3].x = fmaf(t1.x, v.w, a1[3].x); a1[3].y = fmaf(t1.y, v.w, a1[3].y);
        }
#pragma unroll
        for (int j = 0; j < 4; j++) st[o0 * W + w0 + j] = a0[j];
        if (pair) {
#pragma unroll
            for (int j = 0; j < 4; j++) st[o1 * W + w0 + j] = a1[j];
        }
    }
    __syncthreads();
    // stage wfw stride 41
    for (int t = tid; t < W * W; t += 256) {
        int x = t / W, w = t % W;
        swf[x * 41 + w] = g_wfw[t];
    }
    __syncthreads();
    // col DFT: 2o x 4x tiles (210 threads): alpha[o,x] = sum_w st[o,w] * wfw[x,w]
    float2* ap = &g_alpha[(size_t)bid * HW];
    if (tid < 210) {
        int op = tid / 10, xq = tid % 10;
        int o0 = op * 2, x0 = xq * 4;
        bool pair = (o0 + 1) < H;
        int o1 = pair ? o0 + 1 : o0;
        float2 c0[4], c1[4];
#pragma unroll
        for (int j = 0; j < 4; j++) { c0[j] = make_float2(0.f, 0.f); c1[j] = make_float2(0.f, 0.f); }
        for (int w = 0; w < W; w++) {
            float2 s0v = st[o0 * W + w];
            float2 s1v = st[o1 * W + w];
#pragma unroll
            for (int j = 0; j < 4; j++) {
                float2 e = swf[(x0 + j) * 41 + w];
                c0[j] = cmadd(s0v, e, c0[j]);
                c1[j] = cmadd(s1v, e, c1[j]);
            }
        }
#pragma unroll
        for (int j = 0; j < 4; j++) ap[o0 * W + x0 + j] = c0[j];
        if (pair) {
#pragma unroll
            for (int j = 0; j < 4; j++) ap[o1 * W + x0 + j] = c1[j];
        }
    }
}

// ---------------- k_tbS: ALL layers' pole tables + S, one dispatch ----------------
__global__ __launch_bounds__(256) void k_tbS(const float* __restrict__ p1, const float* __restrict__ p2,
                                             const float* __restrict__ res_in) {
    int gb = blockIdx.x;                   // l*C*C + pk
    int l = gb / (C * C), pk = gb % (C * C);
    int tid = threadIdx.x;
    __shared__ float2 sinv1[M1 * H];       // [p*H+o]
    __shared__ float2 sinv2[M2 * W];       // [q*W+x]
    __shared__ float2 sT[M1 * W];
    __shared__ float2 sres[M1 * M2];
    const float* pp1 = p1 + (size_t)gb * M1 * 2;
    const float* pp2 = p2 + (size_t)gb * M2 * 2;
    for (int t = tid; t < M1 * H; t += 256) {
        int p = t / H, o = t % H;
        float pr = pp1[p * 2], pi = pp1[p * 2 + 1];
        int ko = (o <= H / 2) ? o : o - H;           // fftfreq, H=41 odd
        float lam = (40.0f / 41.0f) * (float)ko;     // Im(LAM1)
        float a = -pr, b = lam - pi;
        float d = 1.0f / (a * a + b * b);
        float2 inv = make_float2(a * d, -b * d);
        sinv1[t] = inv;
        float tt = o * (2.0f * PI_F / (H - 1));      // TX[z]
        float er = expf(pr * tt);
        float sn, cs; sincosf(pi * tt, &sn, &cs);
        g_E1a[l][pk][t] = make_float2(er * cs, er * sn);
    }
    for (int t = tid; t < M2 * W; t += 256) {
        int q = t / W, x = t % W;
        float pr = pp2[q * 2], pi = pp2[q * 2 + 1];
        int kx = (x < W / 2) ? x : x - W;            // fftfreq, W=40 even
        float lam = (2.0f * PI_F * 39.0f / 600.0f) * (float)kx;  // Im(LAM2)
        float a = -pr, b = lam - pi;
        float d = 1.0f / (a * a + b * b);
        float2 inv = make_float2(a * d, -b * d);
        sinv2[t] = inv;
        g_inv2a[l][pk][t] = inv;
        float tt = x * (15.0f / (W - 1));            // TY[x]
        float er = expf(pr * tt);
        float sn, cs; sincosf(pi * tt, &sn, &cs);
        g_E2a[l][pk][t] = make_float2(er * cs, er * sn);
    }
    const float2* rp = (const float2*)res_in + (size_t)gb * M1 * M2;
    for (int t = tid; t < M1 * M2; t += 256) sres[t] = rp[t];
    __syncthreads();
    // coalesced transposed inv1 write
    for (int t = tid; t < H * 16; t += 256) {
        int o = t >> 4, p = t & 15;
        g_inv1t[l][pk][t] = (p < M1) ? sinv1[p * H + o] : make_float2(0.f, 0.f);
    }
    // T[p,x] = sum_q res[p,q] inv2[q,x]
    for (int t = tid; t < M1 * W; t += 256) {
        int p = t / W, x = t % W;
        float2 acc = make_float2(0.f, 0.f);
        for (int q = 0; q < M2; q++) acc = cmadd(sres[p * M2 + q], sinv2[q * W + x], acc);
        sT[t] = acc;
    }
    __syncthreads();
    // S[o,x] = sum_p inv1[p,o] * T[p,x]
    float2* sp = g_Sa[l][pk];
    for (int t = tid; t < HW; t += 256) {
        int o = t / W, x = t % W;
        float2 acc = make_float2(0.f, 0.f);
        for (int p = 0; p < M1; p++) acc = cmadd(sinv1[p * H + o], sT[p * W + x], acc);
        sp[t] = acc;
    }
}

// ---------------- k_res1 v3: 2b x 4k register tile ----------------
__global__ __launch_bounds__(256) void k_res1(int l) {
    int bid = blockIdx.x;
    int ch = bid % 7;
    int rest = bid / 7;                            // 0..95
    int kq = rest % 12, bp = rest / 12;            // bp 0..7
    int hw = ch * 256 + threadIdx.x;
    if (hw >= HW) return;
    int b0 = bp * 2, k0 = kq * 4;
    float2 acc[2][4];
#pragma unroll
    for (int u = 0; u < 2; u++)
#pragma unroll
        for (int v = 0; v < 4; v++) acc[u][v] = make_float2(0.f, 0.f);
    for (int i = 0; i < C; i++) {
        float2 a0 = g_alpha[(size_t)((b0    ) * C + i) * HW + hw];
        float2 a1 = g_alpha[(size_t)((b0 + 1) * C + i) * HW + hw];
        float2 s0 = g_Sa[l][i * C + k0][hw];
        float2 s1 = g_Sa[l][i * C + k0 + 1][hw];
        float2 s2 = g_Sa[l][i * C + k0 + 2][hw];
        float2 s3 = g_Sa[l][i * C + k0 + 3][hw];
        acc[0][0] = cmadd(a0, s0, acc[0][0]);
        acc[0][1] = cmadd(a0, s1, acc[0][1]);
        acc[0][2] = cmadd(a0, s2, acc[0][2]);
        acc[0][3] = cmadd(a0, s3, acc[0][3]);
        acc[1][0] = cmadd(a1, s0, acc[1][0]);
        acc[1][1] = cmadd(a1, s1, acc[1][1]);
        acc[1][2] = cmadd(a1, s2, acc[1][2]);
        acc[1][3] = cmadd(a1, s3, acc[1][3]);
    }
#pragma unroll
    for (int u = 0; u < 2; u++)
#pragma unroll
        for (int v = 0; v < 4; v++)
            g_res1[(size_t)((b0 + u) * C + k0 + v) * HW + hw] = acc[u][v];
}

// ---------------- k_ifftfin: x1 = ifft2(res1).real + xparts; stats (fused, tiled) --------
__global__ __launch_bounds__(256) void k_ifftfin() {
    int bid = blockIdx.x; int tid = threadIdx.x;
    __shared__ __align__(16) float2 s0[HW], s1[HW];
    __shared__ __align__(16) float2 swf[H * H];   // wfh; later wfw stride-42
    __shared__ float red[8];
    const float2* rp = &g_res1[(size_t)bid * HW];
    for (int i = tid; i < HW; i += 256) s0[i] = rp[i];
    for (int i = tid; i < H * H; i += 256) swf[i] = g_wfh[i];
    __syncthreads();
    // inverse over o: 2h x 4x tiles (210 threads)
    if (tid < 210) {
        int hp = tid / 10, xq = tid % 10;
        int h0 = hp * 2, x0 = xq * 4;
        bool pair = (h0 + 1) < H;
        int h1 = pair ? h0 + 1 : h0;
        float2 a0[4], a1[4];
#pragma unroll
        for (int j = 0; j < 4; j++) { a0[j] = make_float2(0.f, 0.f); a1[j] = make_float2(0.f, 0.f); }
        for (int o = 0; o < H; o++) {
            float4 v01 = *(const float4*)&s0[o * W + x0];
            float4 v23 = *(const float4*)&s0[o * W + x0 + 2];
            float2 t0 = swf[o * H + h0];
            float2 t1 = swf[o * H + h1];
            a0[0].x = fmaf(v01.x, t0.x, fmaf(v01.y, t0.y, a0[0].x));
            a0[0].y = fmaf(v01.y, t0.x, fmaf(-v01.x, t0.y, a0[0].y));
            a0[1].x = fmaf(v01.z, t0.x, fmaf(v01.w, t0.y, a0[1].x));
            a0[1].y = fmaf(v01.w, t0.x, fmaf(-v01.z, t0.y, a0[1].y));
            a0[2].x = fmaf(v23.x, t0.x, fmaf(v23.y, t0.y, a0[2].x));
            a0[2].y = fmaf(v23.y, t0.x, fmaf(-v23.x, t0.y, a0[2].y));
            a0[3].x = fmaf(v23.z, t0.x, fmaf(v23.w, t0.y, a0[3].x));
            a0[3].y = fmaf(v23.w, t0.x, fmaf(-v23.z, t0.y, a0[3].y));
            a1[0].x = fmaf(v01.x, t1.x, fmaf(v01.y, t1.y, a1[0].x));
            a1[0].y = fmaf(v01.y, t1.x, fmaf(-v01.x, t1.y, a1[0].y));
            a1[1].x = fmaf(v01.z, t1.x, fmaf(v01.w, t1.y, a1[1].x));
            a1[1].y = fmaf(v01.w, t1.x, fmaf(-v01.z, t1.y, a1[1].y));
            a1[2].x = fmaf(v23.x, t1.x, fmaf(v23.y, t1.y, a1[2].x));
            a1[2].y = fmaf(v23.y, t1.x, fmaf(-v23.x, t1.y, a1[2].y));
            a1[3].x = fmaf(v23.z, t1.x, fmaf(v23.w, t1.y, a1[3].x));
            a1[3].y = fmaf(v23.w, t1.x, fmaf(-v23.z, t1.y, a1[3].y));
        }
#pragma unroll
        for (int j = 0; j < 4; j++) s1[h0 * W + x0 + j] = a0[j];
        if (pair) {
#pragma unroll
            for (int j = 0; j < 4; j++) s1[h1 * W + x0 + j] = a1[j];
        }
    }
    __syncthreads();
    // stage wfw stride 42 (16B-aligned rows)
    for (int t = tid; t < W * W; t += 256) {
        int x = t / W, w = t % W;
        swf[x * 42 + w] = g_wfw[t];
    }
    __syncthreads();
    // inverse over x: 2h x 4w tiles + xpart combine + stats
    float* xp = &g_x1[(size_t)bid * HW];
    float s = 0.f, ss = 0.f;
    if (tid < 210) {
        int hp = tid / 10, wq = tid % 10;
        int h0 = hp * 2, w0 = wq * 4;
        bool pair = (h0 + 1) < H;
        int h1 = pair ? h0 + 1 : h0;
        float acc0[4] = {0.f, 0.f, 0.f, 0.f}, acc1[4] = {0.f, 0.f, 0.f, 0.f};
        for (int x = 0; x < W; x++) {
            float2 u0 = s1[h0 * W + x];
            float2 u1 = s1[h1 * W + x];
            float4 e01 = *(const float4*)&swf[x * 42 + w0];
            float4 e23 = *(const float4*)&swf[x * 42 + w0 + 2];
            acc0[0] = fmaf(u0.x, e01.x, fmaf(u0.y, e01.y, acc0[0]));
            acc0[1] = fmaf(u0.x, e01.z, fmaf(u0.y, e01.w, acc0[1]));
            acc0[2] = fmaf(u0.x, e23.x, fmaf(u0.y, e23.y, acc0[2]));
            acc0[3] = fmaf(u0.x, e23.z, fmaf(u0.y, e23.w, acc0[3]));
            acc1[0] = fmaf(u1.x, e01.x, fmaf(u1.y, e01.y, acc1[0]));
            acc1[1] = fmaf(u1.x, e01.z, fmaf(u1.y, e01.w, acc1[1]));
            acc1[2] = fmaf(u1.x, e23.x, fmaf(u1.y, e23.y, acc1[2]));
            acc1[3] = fmaf(u1.x, e23.z, fmaf(u1.y, e23.w, acc1[3]));
        }
        {
            int base = h0 * W + w0;
            float4 q0 = *(const float4*)&g_xpart[0][bid][base];
            float4 q1 = *(const float4*)&g_xpart[1][bid][base];
            float4 q2 = *(const float4*)&g_xpart[2][bid][base];
            float4 q3 = *(const float4*)&g_xpart[3][bid][base];
            float4 q4 = *(const float4*)&g_xpart[4][bid][base];
            float4 q5 = *(const float4*)&g_xpart[5][bid][base];
            float vv[4];
            vv[0] = (acc0[0] + q0.x + q1.x + q2.x + q3.x + q4.x + q5.x) * (1.0f / (H * W));
            vv[1] = (acc0[1] + q0.y + q1.y + q2.y + q3.y + q4.y + q5.y) * (1.0f / (H * W));
            vv[2] = (acc0[2] + q0.z + q1.z + q2.z + q3.z + q4.z + q5.z) * (1.0f / (H * W));
            vv[3] = (acc0[3] + q0.w + q1.w + q2.w + q3.w + q4.w + q5.w) * (1.0f / (H * W));
#pragma unroll
            for (int j = 0; j < 4; j++) { xp[base + j] = vv[j]; s += vv[j]; ss += vv[j] * vv[j]; }
        }
        if (pair) {
            int base = h1 * W + w0;
            float4 q0 = *(const float4*)&g_xpart[0][bid][base];
            float4 q1 = *(const float4*)&g_xpart[1][bid][base];
            float4 q2 = *(const float4*)&g_xpart[2][bid][base];
            float4 q3 = *(const float4*)&g_xpart[3][bid][base];
            float4 q4 = *(const float4*)&g_xpart[4][bid][base];
            float4 q5 = *(const float4*)&g_xpart[5][bid][base];
            float vv[4];
            vv[0] = (acc1[0] + q0.x + q1.x + q2.x + q3.x + q4.x + q5.x) * (1.0f / (H * W));
            vv[1] = (acc1[1] + q0.y + q1.y + q2.y + q3.y + q4.y + q5.y) * (1.0f / (H * W));
            vv[2] = (acc1[2] + q0.z + q1.z + q2.z + q3.z + q4.z + q5.z) * (1.0f / (H * W));
            vv[3] = (acc1[3] + q0.w + q1.w + q2.w + q3.w + q4.w + q5.w) * (1.0f / (H * W));
#pragma unroll
            for (int j = 0; j < 4; j++) { xp[base + j] = vv[j]; s += vv[j]; ss += vv[j] * vv[j]; }
        }
    }
    for (int off = 32; off; off >>= 1) { s += __shfl_down(s, off); ss += __shfl_down(ss, off); }
    if ((tid & 63) == 0) { red[tid >> 6] = s; red[4 + (tid >> 6)] = ss; }
    __syncthreads();
    if (tid == 0) {
        float S = red[0] + red[1] + red[2] + red[3];
        float SS = red[4] + red[5] + red[6] + red[7];
        float mean = S * (1.0f / HW);
        float var = SS * (1.0f / HW) - mean * mean;
        g_mu[bid] = mean; g_rstd[bid] = rsqrtf(var + EPS);
    }
}

// ---------------- k_r2a v8 = v6 + 2-deep alpha prefetch ----------
// grid C*C*4, 320 threads. Y: all lanes (ph2 x bloc4 x x40), 6 p-accs. Z: 288 thr, 2 q-accs.
__global__ __launch_bounds__(320) void k_r2a(const float* __restrict__ res_in, int l) {
    // XCD-aware remap: same-i blocks on one XCD (alpha[:,i] slices L2-resident)
    int bid = blockIdx.x;
    int xcd = bid & 7, idx = bid >> 3;             // idx 0..1151
    int i = (idx / (C * 4)) * 8 + xcd;             // 6 i's per XCD
    int rem = idx % (C * 4);
    int k = rem >> 2;
    int bc = rem & 3;                              // b-chunk: b = bc*4 .. bc*4+3
    int pk = i * C + k;
    int tid = threadIdx.x;
    __shared__ float2 sY[4 * M1 * 41];             // 15.7 KB
    __shared__ float2 si1t[H * 16];                // transposed inv1 [o][p], 16-padded
    __shared__ float2 si2[M2 * 41];                // [q*41 + x]
    __shared__ float2 sres[M1 * M2];
    for (int t = tid; t < H * 16; t += 320) si1t[t] = g_inv1t[l][pk][t];
    for (int t = tid; t < M2 * W; t += 320) {
        int q = t / W, xx = t % W;
        si2[q * 41 + xx] = g_inv2a[l][pk][t];
    }
    const float2* rp = (const float2*)res_in + (size_t)(l * C * C + pk) * M1 * M2;
    for (int t = tid; t < M1 * M2; t += 320) sres[t] = rp[t];
    __syncthreads();
    // ---- Y phase: all 320 threads, 2-deep alpha prefetch ----
    {
        int ph = tid / 160;                        // p-half: p0 = ph*6
        int r2t = tid % 160;
        int bloc = r2t / 40, x = r2t % 40;
        int b = bc * 4 + bloc;
        int p0 = ph * 6;
        const float2* ap = &g_alpha[(size_t)(b * C + i) * HW + x];
        float2 yacc[6];
#pragma unroll
        for (int p = 0; p < 6; p++) yacc[p] = make_float2(0.f, 0.f);
        float2 a_cur = ap[0];
        for (int o = 0; o < H; o++) {
            int onx = (o + 1 < H) ? o + 1 : H - 1;
            float2 a_nxt = ap[onx * W];            // issued before FMAs; retires behind them
            const float4* e4 = (const float4*)&si1t[o * 16 + p0];
            float4 e0 = e4[0], e1 = e4[1], e2 = e4[2];
            yacc[0] = cmadd(make_float2(e0.x, e0.y), a_cur, yacc[0]);
            yacc[1] = cmadd(make_float2(e0.z, e0.w), a_cur, yacc[1]);
            yacc[2] = cmadd(make_float2(e1.x, e1.y), a_cur, yacc[2]);
            yacc[3] = cmadd(make_float2(e1.z, e1.w), a_cur, yacc[3]);
            yacc[4] = cmadd(make_float2(e2.x, e2.y), a_cur, yacc[4]);
            yacc[5] = cmadd(make_float2(e2.z, e2.w), a_cur, yacc[5]);
            a_cur = a_nxt;
        }
#pragma unroll
        for (int p = 0; p < 6; p++) sY[(bloc * M1 + p0 + p) * 41 + x] = yacc[p];
    }
    __syncthreads();
    // ---- Z phase: 288 threads = (bloc4 x p12 x qh6), 2 q-accs ----
    if (tid < 288) {
        int bloc = tid / 72, rem2 = tid % 72;
        int p = rem2 / 6, qh = rem2 % 6;
        int q0 = qh * 2;
        float2 zacc0 = make_float2(0.f, 0.f), zacc1 = make_float2(0.f, 0.f);
        const float2* yrow = &sY[(bloc * M1 + p) * 41];
        const float2* s2a = &si2[q0 * 41];
        const float2* s2b = &si2[(q0 + 1) * 41];
        for (int x = 0; x < W; x++) {
            float2 y = yrow[x];
            zacc0 = cmadd(y, s2a[x], zacc0);
            zacc1 = cmadd(y, s2b[x], zacc1);
        }
        int b = bc * 4 + bloc;
        float2* out = &g_Zr[pk][b * (M1 * M2) + p * M2 + q0];
        out[0] = cmul(sres[p * M2 + q0], zacc0);
        out[1] = cmul(sres[p * M2 + q0 + 1], zacc1);
    }
}

// ---------------- k_r2b: r2[b,k,p,q] = sum_i Zr[i*C+k][b,p,q] ----------------
__global__ __launch_bounds__(256) void k_r2b() {
    int t = blockIdx.x * 256 + threadIdx.x;        // < B*C*144
    if (t >= B * C * M1 * M2) return;
    int pq = t % (M1 * M2);
    int k = (t / (M1 * M2)) % C;
    int b = t / (M1 * M2 * C);
    float2 acc = make_float2(0.f, 0.f);
    for (int i = 0; i < C; i++) {
        float2 v = g_Zr[i * C + k][b * (M1 * M2) + pq];
        acc.x += v.x; acc.y += v.y;
    }
    g_r2[(size_t)(b * C + k) * (M1 * M2) + pq] = acc;
}

// ---------------- k_x2p: 6 parts (grid 4608) ----------
constexpr int XNCI = 2;
__global__ __launch_bounds__(256) void k_x2p(int l) {
    int bid = blockIdx.x;
    int xcd = bid & 7, rest = bid >> 3;            // 0..575
    int part = rest % NPART;
    int idx = rest / NPART;                        // 0..95
    int k = (idx / B) * 8 + xcd;
    int b = idx % B;
    int tid = threadIdx.x;
    __shared__ float2 sE1[XNCI * M1 * 44];         // [jp][z], z-padded to 44 (zeros)
    __shared__ float2 sV [XNCI * M1 * 40];         // [jp][x]
    __shared__ float2 sE2[XNCI * M2 * 41];         // [jq][x]
    __shared__ float2 sr2[XNCI * M1 * M2];
    int xh = tid % 20, zq = tid / 20;              // active: tid<240
    int x0 = xh * 2, z0 = zq * 4;
    float accr[4][2];
#pragma unroll
    for (int zi = 0; zi < 4; zi++) { accr[zi][0] = 0.f; accr[zi][1] = 0.f; }

    int cg0 = part * (C / XNCI / NPART);           // 4 cg groups per part
    for (int cg = cg0; cg < cg0 + C / XNCI / NPART; cg++) {
        for (int t = tid; t < XNCI * M1 * 44; t += 256) {
            int j = t / (M1 * 44), rem = t % (M1 * 44);
            int p = rem / 44, z = rem % 44;
            sE1[t] = (z < H) ? g_E1a[l][(cg * XNCI + j) * C + k][p * H + z]
                             : make_float2(0.f, 0.f);
        }
        for (int t = tid; t < XNCI * M2 * W; t += 256) {
            int j = t / (M2 * W), rem = t % (M2 * W);
            sE2[(t / W) * 41 + (t % W)] = g_E2a[l][(cg * XNCI + j) * C + k][rem];
        }
        for (int t = tid; t < XNCI * M1 * M2; t += 256) {
            int j = t / (M1 * M2);
            sr2[t] = g_r2[(size_t)(b * C + cg * XNCI + j) * (M1 * M2) + (t % (M1 * M2))];
        }
        __syncthreads();
        // V[j,p,x] for p-pairs: one sE2 read feeds 2 outputs
        for (int r = 0; r < 2; r++) {
            int id = tid + r * 256;
            if (id < XNCI * 6 * W) {
                int j = id / (6 * W), rem = id % (6 * W);
                int pp = rem / W, x = rem % W;
                int p0 = pp * 2;
                float2 a0 = make_float2(0.f, 0.f), a1 = make_float2(0.f, 0.f);
#pragma unroll
                for (int q = 0; q < M2; q++) {
                    float2 e = sE2[(j * M2 + q) * 41 + x];
                    a0 = cmadd(sr2[j * (M1 * M2) + p0 * M2 + q], e, a0);
                    a1 = cmadd(sr2[j * (M1 * M2) + (p0 + 1) * M2 + q], e, a1);
                }
                sV[(j * M1 + p0) * 40 + x] = a0;
                sV[(j * M1 + p0 + 1) * 40 + x] = a1;
            }
        }
        __syncthreads();
        // accr[z,x] += Re( E1[jp][z] * V[jp][x] )
        if (tid < 240 && z0 < H) {
            for (int jp = 0; jp < XNCI * M1; jp++) {
                float4 v  = *(const float4*)&sV[jp * 40 + x0];
                float4 eA = *(const float4*)&sE1[jp * 44 + z0];
                float4 eB = *(const float4*)&sE1[jp * 44 + z0 + 2];
                accr[0][0] = fmaf(eA.x, v.x, fmaf(-eA.y, v.y, accr[0][0]));
                accr[0][1] = fmaf(eA.x, v.z, fmaf(-eA.y, v.w, accr[0][1]));
                accr[1][0] = fmaf(eA.z, v.x, fmaf(-eA.w, v.y, accr[1][0]));
                accr[1][1] = fmaf(eA.z, v.z, fmaf(-eA.w, v.w, accr[1][1]));
                accr[2][0] = fmaf(eB.x, v.x, fmaf(-eB.y, v.y, accr[2][0]));
                accr[2][1] = fmaf(eB.x, v.z, fmaf(-eB.y, v.w, accr[2][1]));
                accr[3][0] = fmaf(eB.z, v.x, fmaf(-eB.w, v.y, accr[3][0]));
                accr[3][1] = fmaf(eB.z, v.z, fmaf(-eB.w, v.w, accr[3][1]));
            }
        }
        __syncthreads();
    }
    float* op = &g_xpart[part][b * C + k][0];
    if (tid < 240 && z0 < H) {
#pragma unroll
        for (int zi = 0; zi < 4; zi++) {
            int z = z0 + zi;
            if (z < H) { op[z * W + x0] = accr[zi][0]; op[z * W + x0 + 1] = accr[zi][1]; }
        }
    }
}

// ---------------- h_next = sin( inorm(pr) + conv(h) + conv_b ) ----------------
constexpr int TILE = 128;
constexpr int NTILE = (HW + TILE - 1) / TILE;   // 13
__global__ __launch_bounds__(256) void k_comb(const float* __restrict__ cw,
                                              const float* __restrict__ cb, int l, int src) {
    int b = blockIdx.x / NTILE;
    int t0 = (blockIdx.x % NTILE) * TILE;
    int tid = threadIdx.x;
    __shared__ float shh[C * TILE];
    __shared__ float scw[C * C];
    __shared__ float smu[C], srs[C], scb[C];
    for (int i = tid; i < C * C; i += 256) scw[i] = cw[l * C * C + i];
    for (int i = tid; i < C; i += 256) {
        smu[i] = g_mu[b * C + i]; srs[i] = g_rstd[b * C + i]; scb[i] = cb[l * C + i];
    }
    for (int i = tid; i < C * TILE; i += 256) {
        int c = i / TILE, t = i % TILE; int hw = t0 + t;
        shh[i] = (hw < HW) ? g_h[src][(size_t)(b * C + c) * HW + hw] : 0.f;
    }
    __syncthreads();
    for (int i = tid; i < C * TILE; i += 256) {
        int o = i / TILE, t = i % TILE; int hw = t0 + t;
        if (hw >= HW) continue;
        float acc = scb[o];
        for (int ci = 0; ci < C; ci++) acc = fmaf(scw[o * C + ci], shh[ci * TILE + t], acc);
        float prn = (g_x1[(size_t)(b * C + o) * HW + hw] - smu[o]) * srs[o];
        g_h[src ^ 1][(size_t)(b * C + o) * HW + hw] = sinf(prn + acc);
    }
}

// ---------------- head: out = fc2( sin(fc1(h)) ) ----------------
__global__ __launch_bounds__(256) void k_head(const float* __restrict__ w1, const float* __restrict__ b1,
                                              const float* __restrict__ w2, const float* __restrict__ b2,
                                              float* __restrict__ out, int src) {
    __shared__ float sw1[128 * C];
    __shared__ float sb1[128], sw2[2 * 128];
    int tid = threadIdx.x;
    for (int i = tid; i < 128 * C; i += 256) sw1[i] = w1[i];
    for (int i = tid; i < 128; i += 256) sb1[i] = b1[i];
    for (int i = tid; i < 256; i += 256) sw2[i] = w2[i];
    __syncthreads();
    int pt = blockIdx.x * 256 + tid;               // b*HW + hw
    if (pt >= B * HW) return;
    int b = pt / HW, hw = pt % HW;
    float hv[C];
#pragma unroll
    for (int c = 0; c < C; c++) hv[c] = g_h[src][(size_t)(b * C + c) * HW + hw];
    float o0 = b2[0], o1 = b2[1];
    for (int j = 0; j < 128; j++) {
        float a = sb1[j];
#pragma unroll
        for (int c = 0; c < C; c++) a = fmaf(sw1[j * C + c], hv[c], a);
        float sv = sinf(a);
        o0 = fmaf(sw2[j], sv, o0);
        o1 = fmaf(sw2[128 + j], sv, o1);
    }
    out[pt * 2 + 0] = o0; out[pt * 2 + 1] = o1;
}

// ---------------- launcher ----------------
extern "C" void kernel_launch(void* const* d_in, const int* in_sizes, int n_in,
                              void* d_out, int out_size, void* d_ws, size_t ws_size,
                              hipStream_t stream) {
    const float* x    = (const float*)d_in[0];
    const float* fc0w = (const float*)d_in[1];
    const float* fc0b = (const float*)d_in[2];
    const float* p1   = (const float*)d_in[3];
    const float* p2   = (const float*)d_in[4];
    const float* res  = (const float*)d_in[5];
    const float* cw   = (const float*)d_in[6];
    const float* cb   = (const float*)d_in[7];
    const float* w1   = (const float*)d_in[8];
    const float* b1   = (const float*)d_in[9];
    const float* w2   = (const float*)d_in[10];
    const float* b2   = (const float*)d_in[11];
    float* out = (float*)d_out;

    k_tw<<<(H * H + W * W + 255) / 256, 256, 0, stream>>>();
    k_fc0<<<(B * C * HW + 255) / 256, 256, 0, stream>>>(x, fc0w, fc0b);
    k_tbS<<<NL * C * C, 256, 0, stream>>>(p1, p2, res);   // all layers' tables, once
    int src = 0;
    for (int l = 0; l < NL; l++) {
        k_fft<<<B * C, 256, 0, stream>>>(src);
        k_res1<<<672, 256, 0, stream>>>(l);
        k_r2a<<<C * C * 4, 320, 0, stream>>>(res, l);
        k_r2b<<<(B * C * M1 * M2 + 255) / 256, 256, 0, stream>>>();
        k_x2p<<<NPART * B * C, 256, 0, stream>>>(l);
        k_ifftfin<<<B * C, 256, 0, stream>>>();
        k_comb<<<B * NTILE, 256, 0, stream>>>(cw, cb, l, src);
        src ^= 1;
    }
    k_head<<<(B * HW + 255) / 256, 256, 0, stream>>>(w1, b1, w2, b2, out, src);
}

// Round 15
// 1683.324 us; speedup vs baseline: 1.1493x; 1.0055x over previous
//
#include <hip/hip_runtime.h>
#include <math.h>

#define DI __device__ __forceinline__

constexpr int B = 16, H = 41, W = 40, C = 48, M1 = 12, M2 = 12, NL = 4;
constexpr int HW = H * W;                  // 1640
constexpr int NPART = 6;
constexpr float EPS = 1e-5f;
constexpr float PI_F = 3.14159265358979323846f;

// ---------------- static device scratch (compile-time shapes) ----------------
__device__ float  g_h[2][B * C * HW];      // ping-pong activations [b][c][hw]
__device__ float2 g_alpha[B * C * HW];     // fft2(inorm(h))
__device__ float2 g_inv1t[NL][C * C][H * 16];  // transposed inv1 [o*16+p] (pad 16)
__device__ float2 g_inv2a[NL][C * C][M2 * W];
__device__ float2 g_E1a[NL][C * C][M1 * H];    // [p][z]
__device__ float2 g_E2a[NL][C * C][M2 * W];    // [q][x]
__device__ float2 g_Sa[NL][C * C][HW];
__device__ float2 g_res1[B * C * HW];
__device__ float  g_x1[B * C * HW];        // pr2d output (real)
__device__ float2 g_r2[B * C * M1 * M2];
__device__ float2 g_Zr[C * C][B * M1 * M2]; // per-(i,k) res-scaled Z, reduced over i by k_r2b
__device__ float  g_xpart[NPART][B * C][HW];   // k_x2p partial sums over ci-sixths
__device__ float  g_mu[B * C];
__device__ float  g_rstd[B * C];
__device__ float2 g_wfh[H * H];            // e^{-2pi i o h / H}
__device__ float2 g_wfw[W * W];            // e^{-2pi i x w / W}

// ---------------- complex helpers ----------------
DI float2 cmadd(float2 a, float2 b, float2 acc) {
    acc.x = fmaf(a.x, b.x, fmaf(-a.y, b.y, acc.x));
    acc.y = fmaf(a.x, b.y, fmaf(a.y, b.x, acc.y));
    return acc;
}
DI float2 cmul(float2 a, float2 b) {
    return make_float2(a.x * b.x - a.y * b.y, a.x * b.y + a.y * b.x);
}

// ---------------- twiddle tables ----------------
__global__ void k_tw() {
    int tid = blockIdx.x * 256 + threadIdx.x;
    if (tid < H * H) {
        int o = tid / H, h = tid % H;
        float ph = -2.0f * PI_F * (float)((o * h) % H) / (float)H;
        float s, c; sincosf(ph, &s, &c);
        g_wfh[tid] = make_float2(c, s);
    }
    int t2 = tid - H * H;
    if (t2 >= 0 && t2 < W * W) {
        int o = t2 / W, w = t2 % W;
        float ph = -2.0f * PI_F * (float)((o * w) % W) / (float)W;
        float s, c; sincosf(ph, &s, &c);
        g_wfw[t2] = make_float2(c, s);
    }
}

// ---------------- fc0 + grid concat ----------------
__global__ void k_fc0(const float* __restrict__ x, const float* __restrict__ w,
                      const float* __restrict__ bias) {
    int idx = blockIdx.x * 256 + threadIdx.x;
    if (idx >= B * C * HW) return;
    int hw = idx % HW; int bc = idx / HW; int c = bc % C; int b = bc / C;
    int hh = hw / W, ww = hw % W;
    float xv = x[b * HW + hw];
    float gx = hh * (1.0f / (H - 1));
    float gy = ww * (1.0f / (W - 1));
    g_h[0][idx] = fmaf(w[c * 3 + 0], xv, fmaf(w[c * 3 + 1], gx, fmaf(w[c * 3 + 2], gy, bias[c])));
}

// ---------------- instance-norm + fft2, register-tiled DFTs ----------------
__global__ __launch_bounds__(256) void k_fft(int src) {
    int bid = blockIdx.x;                  // b*C + c
    const float* hp = &g_h[src][(size_t)bid * HW];
    __shared__ __align__(16) float sh[HW];
    __shared__ __align__(16) float2 st[HW];
    __shared__ __align__(16) float2 swf[H * H];   // wfh; later wfw stride-41
    __shared__ float red[8];
    int tid = threadIdx.x;
    float s = 0.f, ss = 0.f;
    for (int i = tid; i < HW; i += 256) { float v = hp[i]; sh[i] = v; s += v; ss += v * v; }
    for (int i = tid; i < H * H; i += 256) swf[i] = g_wfh[i];
    for (int off = 32; off; off >>= 1) { s += __shfl_down(s, off); ss += __shfl_down(ss, off); }
    if ((tid & 63) == 0) { red[tid >> 6] = s; red[4 + (tid >> 6)] = ss; }
    __syncthreads();
    if (tid == 0) {
        float S = red[0] + red[1] + red[2] + red[3];
        float SS = red[4] + red[5] + red[6] + red[7];
        float mean = S * (1.0f / HW);
        float var = SS * (1.0f / HW) - mean * mean;
        red[0] = mean; red[1] = rsqrtf(var + EPS);
    }
    __syncthreads();
    float mean = red[0], rstd = red[1];
    for (int i = tid; i < HW; i += 256) sh[i] = (sh[i] - mean) * rstd;
    __syncthreads();
    // row DFT: 2o x 4w tiles (210 threads): st[o,w] = sum_h wfh[o,h] * sh[h,w]
    if (tid < 210) {
        int op = tid / 10, wq = tid % 10;
        int o0 = op * 2, w0 = wq * 4;
        bool pair = (o0 + 1) < H;
        int o1 = pair ? o0 + 1 : o0;
        float2 a0[4], a1[4];
#pragma unroll
        for (int j = 0; j < 4; j++) { a0[j] = make_float2(0.f, 0.f); a1[j] = make_float2(0.f, 0.f); }
        for (int h = 0; h < H; h++) {
            float4 v = *(const float4*)&sh[h * W + w0];
            float2 t0 = swf[o0 * H + h];
            float2 t1 = swf[o1 * H + h];
            a0[0].x = fmaf(t0.x, v.x, a0[0].x); a0[0].y = fmaf(t0.y, v.x, a0[0].y);
            a0[1].x = fmaf(t0.x, v.y, a0[1].x); a0[1].y = fmaf(t0.y, v.y, a0[1].y);
            a0[2].x = fmaf(t0.x, v.z, a0[2].x); a0[2].y = fmaf(t0.y, v.z, a0[2].y);
            a0[3].x = fmaf(t0.x, v.w, a0[3].x); a0[3].y = fmaf(t0.y, v.w, a0[3].y);
            a1[0].x = fmaf(t1.x, v.x, a1[0].x); a1[0].y = fmaf(t1.y, v.x, a1[0].y);
            a1[1].x = fmaf(t1.x, v.y, a1[1].x); a1[1].y = fmaf(t1.y, v.y, a1[1].y);
            a1[2].x = fmaf(t1.x, v.z, a1[2].x); a1[2].y = fmaf(t1.y, v.z, a1[2].y);
            a1[3].x = fmaf(t1.x, v.w, a1[3].x); a1[3].y = fmaf(t1.y, v.w, a1[3].y);
        }
#pragma unroll
        for (int j = 0; j < 4; j++) st[o0 * W + w0 + j] = a0[j];
        if (pair) {
#pragma unroll
            for (int j = 0; j < 4; j++) st[o1 * W + w0 + j] = a1[j];
        }
    }
    __syncthreads();
    // stage wfw stride 41
    for (int t = tid; t < W * W; t += 256) {
        int x = t / W, w = t % W;
        swf[x * 41 + w] = g_wfw[t];
    }
    __syncthreads();
    // col DFT: 2o x 4x tiles (210 threads): alpha[o,x] = sum_w st[o,w] * wfw[x,w]
    float2* ap = &g_alpha[(size_t)bid * HW];
    if (tid < 210) {
        int op = tid / 10, xq = tid % 10;
        int o0 = op * 2, x0 = xq * 4;
        bool pair = (o0 + 1) < H;
        int o1 = pair ? o0 + 1 : o0;
        float2 c0[4], c1[4];
#pragma unroll
        for (int j = 0; j < 4; j++) { c0[j] = make_float2(0.f, 0.f); c1[j] = make_float2(0.f, 0.f); }
        for (int w = 0; w < W; w++) {
            float2 s0v = st[o0 * W + w];
            float2 s1v = st[o1 * W + w];
#pragma unroll
            for (int j = 0; j < 4; j++) {
                float2 e = swf[(x0 + j) * 41 + w];
                c0[j] = cmadd(s0v, e, c0[j]);
                c1[j] = cmadd(s1v, e, c1[j]);
            }
        }
#pragma unroll
        for (int j = 0; j < 4; j++) ap[o0 * W + x0 + j] = c0[j];
        if (pair) {
#pragma unroll
            for (int j = 0; j < 4; j++) ap[o1 * W + x0 + j] = c1[j];
        }
    }
}

// ---------------- k_tbS: ALL layers' pole tables + S, one dispatch ----------------
__global__ __launch_bounds__(256) void k_tbS(const float* __restrict__ p1, const float* __restrict__ p2,
                                             const float* __restrict__ res_in) {
    int gb = blockIdx.x;                   // l*C*C + pk
    int l = gb / (C * C), pk = gb % (C * C);
    int tid = threadIdx.x;
    __shared__ float2 sinv1[M1 * H];       // [p*H+o]
    __shared__ float2 sinv2[M2 * W];       // [q*W+x]
    __shared__ float2 sT[M1 * W];
    __shared__ float2 sres[M1 * M2];
    const float* pp1 = p1 + (size_t)gb * M1 * 2;
    const float* pp2 = p2 + (size_t)gb * M2 * 2;
    for (int t = tid; t < M1 * H; t += 256) {
        int p = t / H, o = t % H;
        float pr = pp1[p * 2], pi = pp1[p * 2 + 1];
        int ko = (o <= H / 2) ? o : o - H;           // fftfreq, H=41 odd
        float lam = (40.0f / 41.0f) * (float)ko;     // Im(LAM1)
        float a = -pr, b = lam - pi;
        float d = 1.0f / (a * a + b * b);
        float2 inv = make_float2(a * d, -b * d);
        sinv1[t] = inv;
        float tt = o * (2.0f * PI_F / (H - 1));      // TX[z]
        float er = expf(pr * tt);
        float sn, cs; sincosf(pi * tt, &sn, &cs);
        g_E1a[l][pk][t] = make_float2(er * cs, er * sn);
    }
    for (int t = tid; t < M2 * W; t += 256) {
        int q = t / W, x = t % W;
        float pr = pp2[q * 2], pi = pp2[q * 2 + 1];
        int kx = (x < W / 2) ? x : x - W;            // fftfreq, W=40 even
        float lam = (2.0f * PI_F * 39.0f / 600.0f) * (float)kx;  // Im(LAM2)
        float a = -pr, b = lam - pi;
        float d = 1.0f / (a * a + b * b);
        float2 inv = make_float2(a * d, -b * d);
        sinv2[t] = inv;
        g_inv2a[l][pk][t] = inv;
        float tt = x * (15.0f / (W - 1));            // TY[x]
        float er = expf(pr * tt);
        float sn, cs; sincosf(pi * tt, &sn, &cs);
        g_E2a[l][pk][t] = make_float2(er * cs, er * sn);
    }
    const float2* rp = (const float2*)res_in + (size_t)gb * M1 * M2;
    for (int t = tid; t < M1 * M2; t += 256) sres[t] = rp[t];
    __syncthreads();
    // coalesced transposed inv1 write
    for (int t = tid; t < H * 16; t += 256) {
        int o = t >> 4, p = t & 15;
        g_inv1t[l][pk][t] = (p < M1) ? sinv1[p * H + o] : make_float2(0.f, 0.f);
    }
    // T[p,x] = sum_q res[p,q] inv2[q,x]
    for (int t = tid; t < M1 * W; t += 256) {
        int p = t / W, x = t % W;
        float2 acc = make_float2(0.f, 0.f);
        for (int q = 0; q < M2; q++) acc = cmadd(sres[p * M2 + q], sinv2[q * W + x], acc);
        sT[t] = acc;
    }
    __syncthreads();
    // S[o,x] = sum_p inv1[p,o] * T[p,x]
    float2* sp = g_Sa[l][pk];
    for (int t = tid; t < HW; t += 256) {
        int o = t / W, x = t % W;
        float2 acc = make_float2(0.f, 0.f);
        for (int p = 0; p < M1; p++) acc = cmadd(sinv1[p * H + o], sT[p * W + x], acc);
        sp[t] = acc;
    }
}

// ---------------- k_res1 v3: 2b x 4k register tile ----------------
__global__ __launch_bounds__(256) void k_res1(int l) {
    int bid = blockIdx.x;
    int ch = bid % 7;
    int rest = bid / 7;                            // 0..95
    int kq = rest % 12, bp = rest / 12;            // bp 0..7
    int hw = ch * 256 + threadIdx.x;
    if (hw >= HW) return;
    int b0 = bp * 2, k0 = kq * 4;
    float2 acc[2][4];
#pragma unroll
    for (int u = 0; u < 2; u++)
#pragma unroll
        for (int v = 0; v < 4; v++) acc[u][v] = make_float2(0.f, 0.f);
    for (int i = 0; i < C; i++) {
        float2 a0 = g_alpha[(size_t)((b0    ) * C + i) * HW + hw];
        float2 a1 = g_alpha[(size_t)((b0 + 1) * C + i) * HW + hw];
        float2 s0 = g_Sa[l][i * C + k0][hw];
        float2 s1 = g_Sa[l][i * C + k0 + 1][hw];
        float2 s2 = g_Sa[l][i * C + k0 + 2][hw];
        float2 s3 = g_Sa[l][i * C + k0 + 3][hw];
        acc[0][0] = cmadd(a0, s0, acc[0][0]);
        acc[0][1] = cmadd(a0, s1, acc[0][1]);
        acc[0][2] = cmadd(a0, s2, acc[0][2]);
        acc[0][3] = cmadd(a0, s3, acc[0][3]);
        acc[1][0] = cmadd(a1, s0, acc[1][0]);
        acc[1][1] = cmadd(a1, s1, acc[1][1]);
        acc[1][2] = cmadd(a1, s2, acc[1][2]);
        acc[1][3] = cmadd(a1, s3, acc[1][3]);
    }
#pragma unroll
    for (int u = 0; u < 2; u++)
#pragma unroll
        for (int v = 0; v < 4; v++)
            g_res1[(size_t)((b0 + u) * C + k0 + v) * HW + hw] = acc[u][v];
}

// ---------------- k_ifftfin: x1 = ifft2(res1).real + xparts; stats (fused, tiled) --------
__global__ __launch_bounds__(256) void k_ifftfin() {
    int bid = blockIdx.x; int tid = threadIdx.x;
    __shared__ __align__(16) float2 s0[HW], s1[HW];
    __shared__ __align__(16) float2 swf[H * H];   // wfh; later wfw stride-42
    __shared__ float red[8];
    const float2* rp = &g_res1[(size_t)bid * HW];
    for (int i = tid; i < HW; i += 256) s0[i] = rp[i];
    for (int i = tid; i < H * H; i += 256) swf[i] = g_wfh[i];
    __syncthreads();
    // inverse over o: 2h x 4x tiles (210 threads)
    if (tid < 210) {
        int hp = tid / 10, xq = tid % 10;
        int h0 = hp * 2, x0 = xq * 4;
        bool pair = (h0 + 1) < H;
        int h1 = pair ? h0 + 1 : h0;
        float2 a0[4], a1[4];
#pragma unroll
        for (int j = 0; j < 4; j++) { a0[j] = make_float2(0.f, 0.f); a1[j] = make_float2(0.f, 0.f); }
        for (int o = 0; o < H; o++) {
            float4 v01 = *(const float4*)&s0[o * W + x0];
            float4 v23 = *(const float4*)&s0[o * W + x0 + 2];
            float2 t0 = swf[o * H + h0];
            float2 t1 = swf[o * H + h1];
            a0[0].x = fmaf(v01.x, t0.x, fmaf(v01.y, t0.y, a0[0].x));
            a0[0].y = fmaf(v01.y, t0.x, fmaf(-v01.x, t0.y, a0[0].y));
            a0[1].x = fmaf(v01.z, t0.x, fmaf(v01.w, t0.y, a0[1].x));
            a0[1].y = fmaf(v01.w, t0.x, fmaf(-v01.z, t0.y, a0[1].y));
            a0[2].x = fmaf(v23.x, t0.x, fmaf(v23.y, t0.y, a0[2].x));
            a0[2].y = fmaf(v23.y, t0.x, fmaf(-v23.x, t0.y, a0[2].y));
            a0[3].x = fmaf(v23.z, t0.x, fmaf(v23.w, t0.y, a0[3].x));
            a0[3].y = fmaf(v23.w, t0.x, fmaf(-v23.z, t0.y, a0[3].y));
            a1[0].x = fmaf(v01.x, t1.x, fmaf(v01.y, t1.y, a1[0].x));
            a1[0].y = fmaf(v01.y, t1.x, fmaf(-v01.x, t1.y, a1[0].y));
            a1[1].x = fmaf(v01.z, t1.x, fmaf(v01.w, t1.y, a1[1].x));
            a1[1].y = fmaf(v01.w, t1.x, fmaf(-v01.z, t1.y, a1[1].y));
            a1[2].x = fmaf(v23.x, t1.x, fmaf(v23.y, t1.y, a1[2].x));
            a1[2].y = fmaf(v23.y, t1.x, fmaf(-v23.x, t1.y, a1[2].y));
            a1[3].x = fmaf(v23.z, t1.x, fmaf(v23.w, t1.y, a1[3].x));
            a1[3].y = fmaf(v23.w, t1.x, fmaf(-v23.z, t1.y, a1[3].y));
        }
#pragma unroll
        for (int j = 0; j < 4; j++) s1[h0 * W + x0 + j] = a0[j];
        if (pair) {
#pragma unroll
            for (int j = 0; j < 4; j++) s1[h1 * W + x0 + j] = a1[j];
        }
    }
    __syncthreads();
    // stage wfw stride 42 (16B-aligned rows)
    for (int t = tid; t < W * W; t += 256) {
        int x = t / W, w = t % W;
        swf[x * 42 + w] = g_wfw[t];
    }
    __syncthreads();
    // inverse over x: 2h x 4w tiles + xpart combine + stats
    float* xp = &g_x1[(size_t)bid * HW];
    float s = 0.f, ss = 0.f;
    if (tid < 210) {
        int hp = tid / 10, wq = tid % 10;
        int h0 = hp * 2, w0 = wq * 4;
        bool pair = (h0 + 1) < H;
        int h1 = pair ? h0 + 1 : h0;
        float acc0[4] = {0.f, 0.f, 0.f, 0.f}, acc1[4] = {0.f, 0.f, 0.f, 0.f};
        for (int x = 0; x < W; x++) {
            float2 u0 = s1[h0 * W + x];
            float2 u1 = s1[h1 * W + x];
            float4 e01 = *(const float4*)&swf[x * 42 + w0];
            float4 e23 = *(const float4*)&swf[x * 42 + w0 + 2];
            acc0[0] = fmaf(u0.x, e01.x, fmaf(u0.y, e01.y, acc0[0]));
            acc0[1] = fmaf(u0.x, e01.z, fmaf(u0.y, e01.w, acc0[1]));
            acc0[2] = fmaf(u0.x, e23.x, fmaf(u0.y, e23.y, acc0[2]));
            acc0[3] = fmaf(u0.x, e23.z, fmaf(u0.y, e23.w, acc0[3]));
            acc1[0] = fmaf(u1.x, e01.x, fmaf(u1.y, e01.y, acc1[0]));
            acc1[1] = fmaf(u1.x, e01.z, fmaf(u1.y, e01.w, acc1[1]));
            acc1[2] = fmaf(u1.x, e23.x, fmaf(u1.y, e23.y, acc1[2]));
            acc1[3] = fmaf(u1.x, e23.z, fmaf(u1.y, e23.w, acc1[3]));
        }
        {
            int base = h0 * W + w0;
            float4 q0 = *(const float4*)&g_xpart[0][bid][base];
            float4 q1 = *(const float4*)&g_xpart[1][bid][base];
            float4 q2 = *(const float4*)&g_xpart[2][bid][base];
            float4 q3 = *(const float4*)&g_xpart[3][bid][base];
            float4 q4 = *(const float4*)&g_xpart[4][bid][base];
            float4 q5 = *(const float4*)&g_xpart[5][bid][base];
            float vv[4];
            vv[0] = (acc0[0] + q0.x + q1.x + q2.x + q3.x + q4.x + q5.x) * (1.0f / (H * W));
            vv[1] = (acc0[1] + q0.y + q1.y + q2.y + q3.y + q4.y + q5.y) * (1.0f / (H * W));
            vv[2] = (acc0[2] + q0.z + q1.z + q2.z + q3.z + q4.z + q5.z) * (1.0f / (H * W));
            vv[3] = (acc0[3] + q0.w + q1.w + q2.w + q3.w + q4.w + q5.w) * (1.0f / (H * W));
#pragma unroll
            for (int j = 0; j < 4; j++) { xp[base + j] = vv[j]; s += vv[j]; ss += vv[j] * vv[j]; }
        }
        if (pair) {
            int base = h1 * W + w0;
            float4 q0 = *(const float4*)&g_xpart[0][bid][base];
            float4 q1 = *(const float4*)&g_xpart[1][bid][base];
            float4 q2 = *(const float4*)&g_xpart[2][bid][base];
            float4 q3 = *(const float4*)&g_xpart[3][bid][base];
            float4 q4 = *(const float4*)&g_xpart[4][bid][base];
            float4 q5 = *(const float4*)&g_xpart[5][bid][base];
            float vv[4];
            vv[0] = (acc1[0] + q0.x + q1.x + q2.x + q3.x + q4.x + q5.x) * (1.0f / (H * W));
            vv[1] = (acc1[1] + q0.y + q1.y + q2.y + q3.y + q4.y + q5.y) * (1.0f / (H * W));
            vv[2] = (acc1[2] + q0.z + q1.z + q2.z + q3.z + q4.z + q5.z) * (1.0f / (H * W));
            vv[3] = (acc1[3] + q0.w + q1.w + q2.w + q3.w + q4.w + q5.w) * (1.0f / (H * W));
#pragma unroll
            for (int j = 0; j < 4; j++) { xp[base + j] = vv[j]; s += vv[j]; ss += vv[j] * vv[j]; }
        }
    }
    for (int off = 32; off; off >>= 1) { s += __shfl_down(s, off); ss += __shfl_down(ss, off); }
    if ((tid & 63) == 0) { red[tid >> 6] = s; red[4 + (tid >> 6)] = ss; }
    __syncthreads();
    if (tid == 0) {
        float S = red[0] + red[1] + red[2] + red[3];
        float SS = red[4] + red[5] + red[6] + red[7];
        float mean = S * (1.0f / HW);
        float var = SS * (1.0f / HW) - mean * mean;
        g_mu[bid] = mean; g_rstd[bid] = rsqrtf(var + EPS);
    }
}

// ---------------- k_r2a v9: Y phase 160 thr x 2x (halved LDS reads, float4 alpha) --------
// grid C*C*4, 320 threads. Y: 160 thr = (ph2 x bloc4 x xh20), 6p x 2x accs.
// Z: 288 thr, 2 q-accs. LDS unchanged.
__global__ __launch_bounds__(320) void k_r2a(const float* __restrict__ res_in, int l) {
    // XCD-aware remap: same-i blocks on one XCD (alpha[:,i] slices L2-resident)
    int bid = blockIdx.x;
    int xcd = bid & 7, idx = bid >> 3;             // idx 0..1151
    int i = (idx / (C * 4)) * 8 + xcd;             // 6 i's per XCD
    int rem = idx % (C * 4);
    int k = rem >> 2;
    int bc = rem & 3;                              // b-chunk: b = bc*4 .. bc*4+3
    int pk = i * C + k;
    int tid = threadIdx.x;
    __shared__ float2 sY[4 * M1 * 41];             // 15.7 KB
    __shared__ float2 si1t[H * 16];                // transposed inv1 [o][p], 16-padded
    __shared__ float2 si2[M2 * 41];                // [q*41 + x]
    __shared__ float2 sres[M1 * M2];
    for (int t = tid; t < H * 16; t += 320) si1t[t] = g_inv1t[l][pk][t];
    for (int t = tid; t < M2 * W; t += 320) {
        int q = t / W, xx = t % W;
        si2[q * 41 + xx] = g_inv2a[l][pk][t];
    }
    const float2* rp = (const float2*)res_in + (size_t)(l * C * C + pk) * M1 * M2;
    for (int t = tid; t < M1 * M2; t += 320) sres[t] = rp[t];
    __syncthreads();
    // ---- Y phase: 160 active threads, 2 x per thread, 2-deep float4 alpha prefetch ----
    if (tid < 160) {
        int ph = tid / 80;                         // p-half: p0 = ph*6
        int r2t = tid % 80;
        int bloc = r2t / 20, xh = r2t % 20;
        int b = bc * 4 + bloc;
        int p0 = ph * 6;
        int x0 = xh * 2;
        const float4* ap4 = (const float4*)&g_alpha[(size_t)(b * C + i) * HW + x0];  // 16B-aligned
        float2 ya[6], yb[6];                       // accs for x0, x0+1
#pragma unroll
        for (int p = 0; p < 6; p++) { ya[p] = make_float2(0.f, 0.f); yb[p] = make_float2(0.f, 0.f); }
        float4 a_cur = ap4[0];                     // (Re x0, Im x0, Re x0+1, Im x0+1)
        for (int o = 0; o < H; o++) {
            int onx = (o + 1 < H) ? o + 1 : H - 1;
            float4 a_nxt = ap4[onx * (W / 2)];     // W floats2 = W/2 float4 per row
            float2 aA = make_float2(a_cur.x, a_cur.y);
            float2 aB = make_float2(a_cur.z, a_cur.w);
            const float4* e4 = (const float4*)&si1t[o * 16 + p0];
            float4 e0 = e4[0], e1 = e4[1], e2 = e4[2];
            float2 ee;
            ee = make_float2(e0.x, e0.y); ya[0] = cmadd(ee, aA, ya[0]); yb[0] = cmadd(ee, aB, yb[0]);
            ee = make_float2(e0.z, e0.w); ya[1] = cmadd(ee, aA, ya[1]); yb[1] = cmadd(ee, aB, yb[1]);
            ee = make_float2(e1.x, e1.y); ya[2] = cmadd(ee, aA, ya[2]); yb[2] = cmadd(ee, aB, yb[2]);
            ee = make_float2(e1.z, e1.w); ya[3] = cmadd(ee, aA, ya[3]); yb[3] = cmadd(ee, aB, yb[3]);
            ee = make_float2(e2.x, e2.y); ya[4] = cmadd(ee, aA, ya[4]); yb[4] = cmadd(ee, aB, yb[4]);
            ee = make_float2(e2.z, e2.w); ya[5] = cmadd(ee, aA, ya[5]); yb[5] = cmadd(ee, aB, yb[5]);
            a_cur = a_nxt;
        }
#pragma unroll
        for (int p = 0; p < 6; p++) {
            sY[(bloc * M1 + p0 + p) * 41 + x0]     = ya[p];
            sY[(bloc * M1 + p0 + p) * 41 + x0 + 1] = yb[p];
        }
    }
    __syncthreads();
    // ---- Z phase: 288 threads = (bloc4 x p12 x qh6), 2 q-accs ----
    if (tid < 288) {
        int bloc = tid / 72, rem2 = tid % 72;
        int p = rem2 / 6, qh = rem2 % 6;
        int q0 = qh * 2;
        float2 zacc0 = make_float2(0.f, 0.f), zacc1 = make_float2(0.f, 0.f);
        const float2* yrow = &sY[(bloc * M1 + p) * 41];
        const float2* s2a = &si2[q0 * 41];
        const float2* s2b = &si2[(q0 + 1) * 41];
        for (int x = 0; x < W; x++) {
            float2 y = yrow[x];
            zacc0 = cmadd(y, s2a[x], zacc0);
            zacc1 = cmadd(y, s2b[x], zacc1);
        }
        int b = bc * 4 + bloc;
        float2* out = &g_Zr[pk][b * (M1 * M2) + p * M2 + q0];
        out[0] = cmul(sres[p * M2 + q0], zacc0);
        out[1] = cmul(sres[p * M2 + q0 + 1], zacc1);
    }
}

// ---------------- k_r2b: r2[b,k,p,q] = sum_i Zr[i*C+k][b,p,q] ----------------
__global__ __launch_bounds__(256) void k_r2b() {
    int t = blockIdx.x * 256 + threadIdx.x;        // < B*C*144
    if (t >= B * C * M1 * M2) return;
    int pq = t % (M1 * M2);
    int k = (t / (M1 * M2)) % C;
    int b = t / (M1 * M2 * C);
    float2 acc = make_float2(0.f, 0.f);
    for (int i = 0; i < C; i++) {
        float2 v = g_Zr[i * C + k][b * (M1 * M2) + pq];
        acc.x += v.x; acc.y += v.y;
    }
    g_r2[(size_t)(b * C + k) * (M1 * M2) + pq] = acc;
}

// ---------------- k_x2p: 6 parts (grid 4608) ----------
constexpr int XNCI = 2;
__global__ __launch_bounds__(256) void k_x2p(int l) {
    int bid = blockIdx.x;
    int xcd = bid & 7, rest = bid >> 3;            // 0..575
    int part = rest % NPART;
    int idx = rest / NPART;                        // 0..95
    int k = (idx / B) * 8 + xcd;
    int b = idx % B;
    int tid = threadIdx.x;
    __shared__ float2 sE1[XNCI * M1 * 44];         // [jp][z], z-padded to 44 (zeros)
    __shared__ float2 sV [XNCI * M1 * 40];         // [jp][x]
    __shared__ float2 sE2[XNCI * M2 * 41];         // [jq][x]
    __shared__ float2 sr2[XNCI * M1 * M2];
    int xh = tid % 20, zq = tid / 20;              // active: tid<240
    int x0 = xh * 2, z0 = zq * 4;
    float accr[4][2];
#pragma unroll
    for (int zi = 0; zi < 4; zi++) { accr[zi][0] = 0.f; accr[zi][1] = 0.f; }

    int cg0 = part * (C / XNCI / NPART);           // 4 cg groups per part
    for (int cg = cg0; cg < cg0 + C / XNCI / NPART; cg++) {
        for (int t = tid; t < XNCI * M1 * 44; t += 256) {
            int j = t / (M1 * 44), rem = t % (M1 * 44);
            int p = rem / 44, z = rem % 44;
            sE1[t] = (z < H) ? g_E1a[l][(cg * XNCI + j) * C + k][p * H + z]
                             : make_float2(0.f, 0.f);
        }
        for (int t = tid; t < XNCI * M2 * W; t += 256) {
            int j = t / (M2 * W), rem = t % (M2 * W);
            sE2[(t / W) * 41 + (t % W)] = g_E2a[l][(cg * XNCI + j) * C + k][rem];
        }
        for (int t = tid; t < XNCI * M1 * M2; t += 256) {
            int j = t / (M1 * M2);
            sr2[t] = g_r2[(size_t)(b * C + cg * XNCI + j) * (M1 * M2) + (t % (M1 * M2))];
        }
        __syncthreads();
        // V[j,p,x] for p-pairs: one sE2 read feeds 2 outputs
        for (int r = 0; r < 2; r++) {
            int id = tid + r * 256;
            if (id < XNCI * 6 * W) {
                int j = id / (6 * W), rem = id % (6 * W);
                int pp = rem / W, x = rem % W;
                int p0 = pp * 2;
                float2 a0 = make_float2(0.f, 0.f), a1 = make_float2(0.f, 0.f);
#pragma unroll
                for (int q = 0; q < M2; q++) {
                    float2 e = sE2[(j * M2 + q) * 41 + x];
                    a0 = cmadd(sr2[j * (M1 * M2) + p0 * M2 + q], e, a0);
                    a1 = cmadd(sr2[j * (M1 * M2) + (p0 + 1) * M2 + q], e, a1);
                }
                sV[(j * M1 + p0) * 40 + x] = a0;
                sV[(j * M1 + p0 + 1) * 40 + x] = a1;
            }
        }
        __syncthreads();
        // accr[z,x] += Re( E1[jp][z] * V[jp][x] )
        if (tid < 240 && z0 < H) {
            for (int jp = 0; jp < XNCI * M1; jp++) {
                float4 v  = *(const float4*)&sV[jp * 40 + x0];
                float4 eA = *(const float4*)&sE1[jp * 44 + z0];
                float4 eB = *(const float4*)&sE1[jp * 44 + z0 + 2];
                accr[0][0] = fmaf(eA.x, v.x, fmaf(-eA.y, v.y, accr[0][0]));
                accr[0][1] = fmaf(eA.x, v.z, fmaf(-eA.y, v.w, accr[0][1]));
                accr[1][0] = fmaf(eA.z, v.x, fmaf(-eA.w, v.y, accr[1][0]));
                accr[1][1] = fmaf(eA.z, v.z, fmaf(-eA.w, v.w, accr[1][1]));
                accr[2][0] = fmaf(eB.x, v.x, fmaf(-eB.y, v.y, accr[2][0]));
                accr[2][1] = fmaf(eB.x, v.z, fmaf(-eB.y, v.w, accr[2][1]));
                accr[3][0] = fmaf(eB.z, v.x, fmaf(-eB.w, v.y, accr[3][0]));
                accr[3][1] = fmaf(eB.z, v.z, fmaf(-eB.w, v.w, accr[3][1]));
            }
        }
        __syncthreads();
    }
    float* op = &g_xpart[part][b * C + k][0];
    if (tid < 240 && z0 < H) {
#pragma unroll
        for (int zi = 0; zi < 4; zi++) {
            int z = z0 + zi;
            if (z < H) { op[z * W + x0] = accr[zi][0]; op[z * W + x0 + 1] = accr[zi][1]; }
        }
    }
}

// ---------------- h_next = sin( inorm(pr) + conv(h) + conv_b ) ----------------
constexpr int TILE = 128;
constexpr int NTILE = (HW + TILE - 1) / TILE;   // 13
__global__ __launch_bounds__(256) void k_comb(const float* __restrict__ cw,
                                              const float* __restrict__ cb, int l, int src) {
    int b = blockIdx.x / NTILE;
    int t0 = (blockIdx.x % NTILE) * TILE;
    int tid = threadIdx.x;
    __shared__ float shh[C * TILE];
    __shared__ float scw[C * C];
    __shared__ float smu[C], srs[C], scb[C];
    for (int i = tid; i < C * C; i += 256) scw[i] = cw[l * C * C + i];
    for (int i = tid; i < C; i += 256) {
        smu[i] = g_mu[b * C + i]; srs[i] = g_rstd[b * C + i]; scb[i] = cb[l * C + i];
    }
    for (int i = tid; i < C * TILE; i += 256) {
        int c = i / TILE, t = i % TILE; int hw = t0 + t;
        shh[i] = (hw < HW) ? g_h[src][(size_t)(b * C + c) * HW + hw] : 0.f;
    }
    __syncthreads();
    for (int i = tid; i < C * TILE; i += 256) {
        int o = i / TILE, t = i % TILE; int hw = t0 + t;
        if (hw >= HW) continue;
        float acc = scb[o];
        for (int ci = 0; ci < C; ci++) acc = fmaf(scw[o * C + ci], shh[ci * TILE + t], acc);
        float prn = (g_x1[(size_t)(b * C + o) * HW + hw] - smu[o]) * srs[o];
        g_h[src ^ 1][(size_t)(b * C + o) * HW + hw] = sinf(prn + acc);
    }
}

// ---------------- head: out = fc2( sin(fc1(h)) ) ----------------
__global__ __launch_bounds__(256) void k_head(const float* __restrict__ w1, const float* __restrict__ b1,
                                              const float* __restrict__ w2, const float* __restrict__ b2,
                                              float* __restrict__ out, int src) {
    __shared__ float sw1[128 * C];
    __shared__ float sb1[128], sw2[2 * 128];
    int tid = threadIdx.x;
    for (int i = tid; i < 128 * C; i += 256) sw1[i] = w1[i];
    for (int i = tid; i < 128; i += 256) sb1[i] = b1[i];
    for (int i = tid; i < 256; i += 256) sw2[i] = w2[i];
    __syncthreads();
    int pt = blockIdx.x * 256 + tid;               // b*HW + hw
    if (pt >= B * HW) return;
    int b = pt / HW, hw = pt % HW;
    float hv[C];
#pragma unroll
    for (int c = 0; c < C; c++) hv[c] = g_h[src][(size_t)(b * C + c) * HW + hw];
    float o0 = b2[0], o1 = b2[1];
    for (int j = 0; j < 128; j++) {
        float a = sb1[j];
#pragma unroll
        for (int c = 0; c < C; c++) a = fmaf(sw1[j * C + c], hv[c], a);
        float sv = sinf(a);
        o0 = fmaf(sw2[j], sv, o0);
        o1 = fmaf(sw2[128 + j], sv, o1);
    }
    out[pt * 2 + 0] = o0; out[pt * 2 + 1] = o1;
}

// ---------------- launcher ----------------
extern "C" void kernel_launch(void* const* d_in, const int* in_sizes, int n_in,
                              void* d_out, int out_size, void* d_ws, size_t ws_size,
                              hipStream_t stream) {
    const float* x    = (const float*)d_in[0];
    const float* fc0w = (const float*)d_in[1];
    const float* fc0b = (const float*)d_in[2];
    const float* p1   = (const float*)d_in[3];
    const float* p2   = (const float*)d_in[4];
    const float* res  = (const float*)d_in[5];
    const float* cw   = (const float*)d_in[6];
    const float* cb   = (const float*)d_in[7];
    const float* w1   = (const float*)d_in[8];
    const float* b1   = (const float*)d_in[9];
    const float* w2   = (const float*)d_in[10];
    const float* b2   = (const float*)d_in[11];
    float* out = (float*)d_out;

    k_tw<<<(H * H + W * W + 255) / 256, 256, 0, stream>>>();
    k_fc0<<<(B * C * HW + 255) / 256, 256, 0, stream>>>(x, fc0w, fc0b);
    k_tbS<<<NL * C * C, 256, 0, stream>>>(p1, p2, res);   // all layers' tables, once
    int src = 0;
    for (int l = 0; l < NL; l++) {
        k_fft<<<B * C, 256, 0, stream>>>(src);
        k_res1<<<672, 256, 0, stream>>>(l);
        k_r2a<<<C * C * 4, 320, 0, stream>>>(res, l);
        k_r2b<<<(B * C * M1 * M2 + 255) / 256, 256, 0, stream>>>();
        k_x2p<<<NPART * B * C, 256, 0, stream>>>(l);
        k_ifftfin<<<B * C, 256, 0, stream>>>();
        k_comb<<<B * NTILE, 256, 0, stream>>>(cw, cb, l, src);
        src ^= 1;
    }
    k_head<<<(B * HW + 255) / 256, 256, 0, stream>>>(w1, b1, w2, b2, out, src);
}